// Round 10
// baseline (283.274 us; speedup 1.0000x reference)
//
#include <hip/hip_runtime.h>
#include <math.h>

#define BB 4
#define LQ 8400
#define NH 8
#define LVTOT 8500
#define HD 32
#define PLANE_USH 544000   // 8500 pairs x 64 ushorts (2 parity copies of 4250)

typedef __attribute__((ext_vector_type(8))) short short8;
typedef __attribute__((ext_vector_type(4))) float f32x4;
typedef __attribute__((ext_vector_type(2))) _Float16 half2_t;
typedef __attribute__((ext_vector_type(2))) __fp16 fp16x2_t;
typedef unsigned short ushort_t;

__device__ __forceinline__ ushort_t f2bf(float f) {
    union { float f; unsigned u; } v; v.f = f;
    unsigned r = v.u + 0x7fffu + ((v.u >> 16) & 1u);   // RNE
    return (ushort_t)(r >> 16);
}
__device__ __forceinline__ float bflo(unsigned u) {
    union { unsigned u; float f; } x; x.u = u << 16; return x.f;
}
__device__ __forceinline__ float bfhi(unsigned u) {
    union { unsigned u; float f; } x; x.u = u & 0xffff0000u; return x.f;
}
__device__ __forceinline__ half2_t ash2(unsigned u) {
    union { unsigned u; half2_t h; } x; x.u = u; return x.h;
}
__device__ __forceinline__ unsigned pk2u(fp16x2_t h) {
    union { fp16x2_t h; unsigned u; } x; x.h = h; return x.u;
}

// async global->LDS DMA, 16 B per lane (wave-uniform LDS base + lane*16)
__device__ __forceinline__ void dma16(const ushort_t* g, ushort_t* l) {
    __builtin_amdgcn_global_load_lds(
        (const __attribute__((address_space(1))) void*)g,
        (__attribute__((address_space(3))) void*)l, 16, 0, 0);
}

// level decomposition of a pixel index (0..8499) -> pair-space geometry
__device__ __forceinline__ void lvl_decomp(int pix, int& lb, int& y, int& x,
                                           int& rowp) {
    if (pix < 6400)      { y = pix / 80;            x = pix - y * 80;  rowp = 40; lb = 0; }
    else if (pix < 8000) { int r = pix - 6400; y = r / 40; x = r - y * 40; rowp = 20; lb = 3200; }
    else if (pix < 8400) { int r = pix - 8000; y = r / 20; x = r - y * 20; rowp = 10; lb = 4000; }
    else                 { int r = pix - 8400; y = r / 10; x = r - y * 10; rowp = 5;  lb = 4200; }
}

// ---------------------------------------------------------------------------
// Merged prep: blocks [0,8500) cast value, [8500,16900) cast query,
// [16900,17796) build BT (transposed bf16 weights, 896 rows x 256 k).
// ---------------------------------------------------------------------------
__global__ __launch_bounds__(256) void prep_all(
    const float* __restrict__ value, const float* __restrict__ query,
    const float* __restrict__ Wv, const float* __restrict__ Woff,
    const float* __restrict__ Wattn, const float* __restrict__ Wo,
    ushort_t* __restrict__ value_b, ushort_t* __restrict__ query_b,
    ushort_t* __restrict__ BT)
{
    const int bid = blockIdx.x;
    if (bid < 16900) {
        const float* src = (bid < 8500) ? value : query;
        ushort_t* dst = (bid < 8500) ? value_b : query_b;
        int i = (bid < 8500 ? bid : bid - 8500) * 256 + threadIdx.x;
        float4 f = ((const float4*)src)[i];
        ushort4 o;
        o.x = f2bf(f.x); o.y = f2bf(f.y); o.z = f2bf(f.z); o.w = f2bf(f.w);
        ((ushort4*)dst)[i] = o;
    } else {
        int idx = (bid - 16900) * 256 + threadIdx.x;   // 896*256
        int r = idx >> 8, k = idx & 255;
        float v;
        if (r < 256) v = Wv[k * 256 + r];
        else if (r < 640) {
            int n = r - 256;
            v = (n < 256) ? Woff[k * 256 + n] : Wattn[k * 128 + (n - 256)];
        } else v = Wo[k * 256 + (r - 640)];
        BT[idx] = f2bf(v);
    }
}

// ---------------------------------------------------------------------------
// GEMM core v4 (B-direct): 128x128 tile, 4 waves, BK=64, serial 2-barrier
// loop. Only A is staged in LDS (4 dma16/step); B fragments are read
// straight from global — BT is 448 KB, L2-resident, addresses loop-
// invariant so the compiler hoists/pipelines them. Halved LDS -> more
// blocks/CU -> drain latency hidden by TLP (m114 mechanism).
// ---------------------------------------------------------------------------
__device__ __forceinline__ void gemm_core_bd(
    const ushort_t* __restrict__ A, const ushort_t* __restrict__ B, int M,
    int m0, int n0, ushort_t* Asl, f32x4 acc[4][4])
{
    const int tid  = threadIdx.x;
    const int wave = tid >> 6, lane = tid & 63;
    const int quad = lane >> 4, mr = lane & 15;
    const int wm   = (wave >> 1) * 64, wn = (wave & 1) * 64;
    const int oct  = lane >> 3;       // 0..7 row-in-wave-slab
    const int bseg = lane & 7;        // physical 16B slot within row

    for (int k0 = 0; k0 < 256; k0 += 64) {
        __syncthreads();              // prior iteration's reads done
        #pragma unroll
        for (int i = 0; i < 4; i++) {
            int m  = i * 32 + wave * 8 + oct;          // block-relative row
            int gs = bseg ^ (m & 7);                   // swizzled source seg
            int am = min(m0 + m, M - 1);
            dma16(A + (size_t)am * 256 + k0 + gs * 8,
                  Asl + (i * 32 + wave * 8) * 64 + lane * 8);
        }
        __syncthreads();              // DMA landed
        #pragma unroll
        for (int ks = 0; ks < 2; ks++) {
            short8 af[4], bf[4];
            const int ksl = ks * 4 + quad;
            #pragma unroll
            for (int i = 0; i < 4; i++) {
                int m = wm + i * 16 + mr;
                af[i] = *(const short8*)&Asl[m * 64 + (ksl ^ (m & 7)) * 8];
                int n = wn + i * 16 + mr;
                bf[i] = *(const short8*)&B[(size_t)(n0 + n) * 256 + k0 + ksl * 8];
            }
            #pragma unroll
            for (int i = 0; i < 4; i++)
                #pragma unroll
                for (int j = 0; j < 4; j++)
                    acc[i][j] = __builtin_amdgcn_mfma_f32_16x16x32_bf16(
                        af[i], bf[j], acc[i][j], 0, 0, 0);
        }
    }
}

// ---------------------------------------------------------------------------
// Fused GEMM1 (value->vperm f16 pair-interleaved x2 parity) + GEMM2
// (query->off/awl). LDS-repack epilogue (round-8 proven): acc staged into
// a swizzled 128x128 f16 LDS tile, then coalesced stores: mode1 row-major
// 16B; mode0 pair-major units + 2x128 boundary 2B scatters. Wrap pairs
// (never read by the sampler) skipped.
// ---------------------------------------------------------------------------
__global__ __launch_bounds__(256, 4) void gemm_fused(
    const ushort_t* __restrict__ Av, const ushort_t* __restrict__ Aq,
    const ushort_t* __restrict__ BT,
    const float* __restrict__ bv, const float* __restrict__ boff,
    const float* __restrict__ battn,
    ushort_t* __restrict__ vperm, ushort_t* __restrict__ off_b,
    ushort_t* __restrict__ awl_b)
{
    __shared__ ushort_t smem[16384];   // K-loop: A stage (first 8192); epi: 128x128

    const int bid = blockIdx.x;
    int mode, m0, n0, M;
    const ushort_t *A, *B;
    if (bid < 532) { mode = 0; m0 = (bid >> 1) * 128; n0 = (bid & 1) * 128;
                     A = Av; B = BT; M = 34000; }
    else { int b2 = bid - 532;
           mode = 1; m0 = (b2 / 3) * 128; n0 = (b2 % 3) * 128;
           A = Aq; B = BT + 65536; M = 33600; }

    f32x4 acc[4][4];
    #pragma unroll
    for (int i = 0; i < 4; i++)
        #pragma unroll
        for (int j = 0; j < 4; j++) acc[i][j] = (f32x4){0.f, 0.f, 0.f, 0.f};

    gemm_core_bd(A, B, M, m0, n0, smem, acc);

    const int tid  = threadIdx.x;
    const int wave = tid >> 6, lane = tid & 63;
    const int quad = lane >> 4, mr = lane & 15;
    const int wm   = (wave >> 1) * 64, wn = (wave & 1) * 64;

    // ---- step 1: acc (+bias, cvt) -> swizzled LDS tile ----
    __syncthreads();                   // last K-step's LDS reads done
    #pragma unroll
    for (int i = 0; i < 4; i++) {
        #pragma unroll
        for (int j = 0; j < 4; j++) {
            const int lc = wn + j * 16 + mr;
            const int c  = n0 + lc;
            const float bias = (mode == 0) ? bv[c]
                              : (c < 256 ? boff[c] : battn[c - 256]);
            #pragma unroll
            for (int reg = 0; reg < 4; reg++) {
                const int rl = wm + i * 16 + quad * 4 + reg;
                float val = acc[i][j][reg] + bias;
                ushort_t u;
                if (mode == 0) { union { _Float16 h; ushort_t u; } cv;
                                 cv.h = (_Float16)val; u = cv.u; }
                else u = f2bf(val);
                smem[rl * 128 + (lc ^ ((rl & 3) << 3))] = u;
            }
        }
    }
    __syncthreads();

    // ---- step 2: coalesced stores ----
    if (mode == 1) {
        for (int k = 0; k < 8; k++) {
            int sid = k * 256 + tid;            // 2048 x 16B
            int rl = sid >> 4, cc = (sid & 15) * 8;
            int row = m0 + rl;
            if (row >= M) continue;
            uint4 v = *(const uint4*)&smem[rl * 128 + (cc ^ ((rl & 3) << 3))];
            if (n0 < 256) *(uint4*)&off_b[(size_t)row * 256 + n0 + cc] = v;
            else          *(uint4*)&awl_b[(size_t)row * 128 + cc] = v;
        }
    } else {
        const int hb = n0 >> 5;                 // head base: 0 or 4
        // complete pairs: units 0..63 copy0 (t=2u), 64..126 copy1 (t=2u+1)
        for (int k = 0; k < 16; k++) {
            int sid = k * 256 + tid;            // 4096 slots, 127*32 used
            int unit = sid >> 5;
            if (unit >= 127) continue;
            int sub = sid & 31;
            int hh = sub >> 3, q = sub & 7;
            int copy = (unit >= 64) ? 1 : 0;
            int t = copy ? ((unit - 64) * 2 + 1) : (unit * 2);
            int row = m0 + t;
            if (row + 1 >= 34000) continue;     // need both pixels
            int b = row / LVTOT, pix = row - b * LVTOT;
            int lb, y, x, rowp;
            lvl_decomp(pix, lb, y, x, rowp);
            if (copy && x >= 2 * rowp - 1) continue;   // wrap pair: never read
            int p = x >> 1;                     // (x even: x/2) | (x odd: (x-1)/2)
            int pidx = copy * 4250 + lb + y * rowp + p;
            int h = hb + hh;
            uint2 a  = *(const uint2*)&smem[t * 128 +
                          ((hh * 32 + q * 4) ^ ((t & 3) << 3))];
            uint2 b2 = *(const uint2*)&smem[(t + 1) * 128 +
                          ((hh * 32 + q * 4) ^ (((t + 1) & 3) << 3))];
            uint4 o;
            o.x = (a.x & 0xffffu) | (b2.x << 16);
            o.y = (a.x >> 16)     | (b2.x & 0xffff0000u);
            o.z = (a.y & 0xffffu) | (b2.y << 16);
            o.w = (a.y >> 16)     | (b2.y & 0xffff0000u);
            *(uint4*)((char*)(vperm + (size_t)(b * NH + h) * PLANE_USH)
                      + (size_t)pidx * 128 + q * 16) = o;
        }
        // boundary scatters: pixel t=0 -> slot1 of left pair; t=127 -> slot0
        {
            int pixsel = tid >> 7;              // 0: t=0, 1: t=127
            int rem = tid & 127;
            int hh = rem >> 5, d = rem & 31;
            int t = pixsel ? 127 : 0;
            int row = m0 + t;
            if (row < 34000) {
                int b = row / LVTOT, pix = row - b * LVTOT;
                int lb, y, x, rowp;
                lvl_decomp(pix, lb, y, x, rowp);
                bool doit; int p, slot;
                if (!pixsel) { doit = (x >= 2);            p = (x - 2) >> 1; slot = 1; }
                else         { doit = (x < 2 * rowp - 1);  p = (x - 1) >> 1; slot = 0; }
                if (doit) {
                    int pidx = 4250 + lb + y * rowp + p;
                    int h = hb + hh;
                    vperm[(size_t)(b * NH + h) * PLANE_USH
                          + (size_t)pidx * 64 + d * 2 + slot] =
                        smem[t * 128 + ((hh * 32 + d) ^ ((t & 3) << 3))];
                }
            }
        }
    }
}

// ---------------------------------------------------------------------------
// GEMM3: sampled(bf16) @ Wo + bo -> out fp32 (stores already coalesced)
// ---------------------------------------------------------------------------
__global__ __launch_bounds__(256, 6) void gemm_out(
    const ushort_t* __restrict__ A, const ushort_t* __restrict__ BT,
    const float* __restrict__ bo, float* __restrict__ out)
{
    __shared__ ushort_t Asl[128 * 64];

    const int m0 = (blockIdx.x >> 1) * 128;    // adjacency swizzle (263x2)
    const int n0 = (blockIdx.x & 1) * 128;
    const int M = 33600;

    f32x4 acc[4][4];
    #pragma unroll
    for (int i = 0; i < 4; i++)
        #pragma unroll
        for (int j = 0; j < 4; j++) acc[i][j] = (f32x4){0.f, 0.f, 0.f, 0.f};

    gemm_core_bd(A, BT, M, m0, n0, Asl, acc);

    const int tid  = threadIdx.x;
    const int wave = tid >> 6, lane = tid & 63;
    const int quad = lane >> 4, mr = lane & 15;
    const int wm   = (wave >> 1) * 64, wn = (wave & 1) * 64;

    #pragma unroll
    for (int i = 0; i < 4; i++) {
        const int rbase = m0 + wm + i * 16 + quad * 4;
        #pragma unroll
        for (int j = 0; j < 4; j++) {
            const int c = n0 + wn + j * 16 + mr;
            #pragma unroll
            for (int reg = 0; reg < 4; reg++) {
                int row = rbase + reg;
                if (row >= M) continue;
                out[(size_t)row * 256 + c] = acc[i][j][reg] + bo[c];
            }
        }
    }
}

// ---------------------------------------------------------------------------
// Sampler v10 (unchanged, proven 47.9 µs): pair-interleaved gathers, plane-
// locality blocks (b, h, 32-query chunk), h = bid&7 XCD-pinned.
// ---------------------------------------------------------------------------
__global__ __launch_bounds__(256) void msda_sample(
    const ushort_t* __restrict__ vperm, const ushort_t* __restrict__ off,
    const ushort_t* __restrict__ awl, const float* __restrict__ refp,
    ushort_t* __restrict__ sampled)
{
    __shared__ int4 s_wi[16 * 33];   // (wt f16x2, wb f16x2, off_top, off_bot)

    const int tid = threadIdx.x;
    const int bid = blockIdx.x;
    const int h   = bid & 7;          // XCD-pinned head
    const int r   = bid >> 3;         // 0..1051
    const int b   = r / 263;
    const int c   = r - b * 263;      // chunk within batch
    const int q0b = c * 32;           // first query (within batch b)
    const size_t bq0 = (size_t)b * LQ + q0b;

    const int Hs[4]    = {80, 40, 20, 10};
    const int pbase[4] = {0, 3200, 4000, 4200};

    #pragma unroll
    for (int it = 0; it < 2; it++) {
        const int s  = it * 256 + tid;
        const int ql = s >> 4, lp = s & 15;
        const int l  = lp >> 2;
        const int qv = (q0b + ql < LQ) ? ql : 0;   // clamp tail chunk reads
        const size_t bq = bq0 + qv;
        const int Wl = Hs[l];

        unsigned od = *(const unsigned*)(off + bq * 256 + h * 32 + lp * 2);
        float ox = bflo(od), oy = bfhi(od);
        float lgt = bflo((unsigned)awl[bq * 128 + h * 16 + lp]);
        // softmax over the 16-lane (q) group, no max pass (bounded logits)
        float e = __expf(lgt);
        float sum = e;
        sum += __shfl_xor(sum, 1, 16);
        sum += __shfl_xor(sum, 2, 16);
        sum += __shfl_xor(sum, 4, 16);
        sum += __shfl_xor(sum, 8, 16);
        float aw = e * __builtin_amdgcn_rcpf(sum);

        float2 rp = *(const float2*)(refp + bq * 8 + l * 2);
        float x = rp.x * (float)Wl + ox - 0.5f;
        float y = rp.y * (float)Wl + oy - 0.5f;
        float x0f = floorf(x), y0f = floorf(y);
        float wx = x - x0f, wy = y - y0f;
        int x0 = (int)x0f, y0 = (int)y0f;
        float hx0 = ((x0 >= 0) & (x0 < Wl)) ? (1.f - wx) : 0.f;
        float hx1 = ((x0 + 1 >= 0) & (x0 + 1 < Wl)) ? wx : 0.f;
        float vy0w = ((y0 >= 0) & (y0 < Wl)) ? (1.f - wy) * aw : 0.f;
        float vy1w = ((y0 + 1 >= 0) & (y0 + 1 < Wl)) ? wy * aw : 0.f;
        // fold borders into a valid adjacent pair (px, px+1)
        int px = min(max(x0, 0), Wl - 2);
        float pl, pr;
        if (x0 < px)      { pl = hx1; pr = 0.f; }   // x0 left of grid
        else if (x0 > px) { pl = 0.f; pr = hx0; }   // x0 == Wl-1
        else              { pl = hx0; pr = hx1; }
        int cy0 = min(max(y0, 0), Wl - 1);
        int cy1 = min(max(y0 + 1, 0), Wl - 1);
        const int copy = px & 1;
        const int p    = copy ? ((px - 1) >> 1) : (px >> 1);
        const int rowp = Wl >> 1;
        const int cb   = copy * 4250 + pbase[l] + p;
        const int otop = (cb + cy0 * rowp) << 7;    // pair byte offsets
        const int obot = (cb + cy1 * rowp) << 7;
        unsigned wt = pk2u(__builtin_amdgcn_cvt_pkrtz(pl * vy0w, pr * vy0w));
        unsigned wb = pk2u(__builtin_amdgcn_cvt_pkrtz(pl * vy1w, pr * vy1w));
        s_wi[lp * 33 + ql] = make_int4((int)wt, (int)wb, otop, obot);
    }
    __syncthreads();

    const int ql  = tid >> 3;          // 0..31
    const int l8  = tid & 7;
    const int dby = l8 * 16;           // byte offset of this lane's 4-dim pair block

    if (q0b + ql < LQ) {
        const char* plane = (const char*)(vperm + (size_t)(b * NH + h) * PLANE_USH);
        float a0 = 0.f, a1 = 0.f, a2 = 0.f, a3 = 0.f;
        #pragma unroll
        for (int pt = 0; pt < 16; pt++) {
            int4 wi = s_wi[pt * 33 + ql];
            uint4 vt = *(const uint4*)(plane + (unsigned)(wi.z + dby));
            uint4 vb = *(const uint4*)(plane + (unsigned)(wi.w + dby));
            half2_t wt = ash2((unsigned)wi.x);
            half2_t wb = ash2((unsigned)wi.y);
            a0 = __builtin_amdgcn_fdot2(wt, ash2(vt.x), a0, false);
            a0 = __builtin_amdgcn_fdot2(wb, ash2(vb.x), a0, false);
            a1 = __builtin_amdgcn_fdot2(wt, ash2(vt.y), a1, false);
            a1 = __builtin_amdgcn_fdot2(wb, ash2(vb.y), a1, false);
            a2 = __builtin_amdgcn_fdot2(wt, ash2(vt.z), a2, false);
            a2 = __builtin_amdgcn_fdot2(wb, ash2(vb.z), a2, false);
            a3 = __builtin_amdgcn_fdot2(wt, ash2(vt.w), a3, false);
            a3 = __builtin_amdgcn_fdot2(wb, ash2(vb.w), a3, false);
        }
        const size_t bq = bq0 + ql;
        ushort4 o;
        o.x = f2bf(a0); o.y = f2bf(a1);
        o.z = f2bf(a2); o.w = f2bf(a3);
        *(ushort4*)(sampled + bq * 256 + h * 32 + l8 * 4) = o;
    }
}

extern "C" void kernel_launch(void* const* d_in, const int* in_sizes, int n_in,
                              void* d_out, int out_size, void* d_ws, size_t ws_size,
                              hipStream_t stream) {
    const float* query = (const float*)d_in[0];
    const float* refp  = (const float*)d_in[1];
    const float* value = (const float*)d_in[2];
    const float* Wv    = (const float*)d_in[4];
    const float* bv    = (const float*)d_in[5];
    const float* Woff  = (const float*)d_in[6];
    const float* boff  = (const float*)d_in[7];
    const float* Wattn = (const float*)d_in[8];
    const float* battn = (const float*)d_in[9];
    const float* Wo    = (const float*)d_in[10];
    const float* bo    = (const float*)d_in[11];
    float* out = (float*)d_out;

    // Workspace (95.7 MB): off 17.2 + awl 8.6 + value_b 17.4 + query_b 17.2
    //                      + vperm(pair x2) 34.8 + BT 0.46
    ushort_t* ws = (ushort_t*)d_ws;
    ushort_t* off_b   = ws;                       // 33600*256
    ushort_t* awl_b   = off_b + 8601600;          // 33600*128
    ushort_t* value_b = awl_b + 4300800;          // 34000*256
    ushort_t* query_b = value_b + 8704000;        // 33600*256 (aliased w/ sampled)
    ushort_t* vperm_b = query_b + 8601600;        // 32 planes * 544000 (f16 pairs)
    ushort_t* BT      = vperm_b + 17408000;       // 896*256
    ushort_t* sampled_b = query_b;                // alias: query dead after gemm_fused

    prep_all<<<dim3(17796), 256, 0, stream>>>(
        value, query, Wv, Woff, Wattn, Wo, value_b, query_b, BT);

    gemm_fused<<<dim3(532 + 789), 256, 0, stream>>>(
        value_b, query_b, BT, bv, boff, battn, vperm_b, off_b, awl_b);

    msda_sample<<<dim3(8 * 4 * 263), 256, 0, stream>>>(
        vperm_b, off_b, awl_b, refp, sampled_b);

    gemm_out<<<dim3(526), 256, 0, stream>>>(
        sampled_b, BT + 163840, bo, out);
}

// Round 11
// 212.943 us; speedup vs baseline: 1.3303x; 1.3303x over previous
//
#include <hip/hip_runtime.h>
#include <math.h>

#define BB 4
#define LQ 8400
#define NH 8
#define LVTOT 8500
#define HD 32
#define PLANE_USH 544000   // 8500 pairs x 64 ushorts (2 parity copies of 4250)

typedef __attribute__((ext_vector_type(8))) short short8;
typedef __attribute__((ext_vector_type(4))) float f32x4;
typedef __attribute__((ext_vector_type(2))) _Float16 half2_t;
typedef __attribute__((ext_vector_type(2))) __fp16 fp16x2_t;
typedef unsigned short ushort_t;

__device__ __forceinline__ ushort_t f2bf(float f) {
    union { float f; unsigned u; } v; v.f = f;
    unsigned r = v.u + 0x7fffu + ((v.u >> 16) & 1u);   // RNE
    return (ushort_t)(r >> 16);
}
__device__ __forceinline__ float bflo(unsigned u) {
    union { unsigned u; float f; } x; x.u = u << 16; return x.f;
}
__device__ __forceinline__ float bfhi(unsigned u) {
    union { unsigned u; float f; } x; x.u = u & 0xffff0000u; return x.f;
}
__device__ __forceinline__ half2_t ash2(unsigned u) {
    union { unsigned u; half2_t h; } x; x.u = u; return x.h;
}
__device__ __forceinline__ unsigned pk2u(fp16x2_t h) {
    union { fp16x2_t h; unsigned u; } x; x.h = h; return x.u;
}

// async global->LDS DMA, 16 B per lane (wave-uniform LDS base + lane*16)
__device__ __forceinline__ void dma16(const ushort_t* g, ushort_t* l) {
    __builtin_amdgcn_global_load_lds(
        (const __attribute__((address_space(1))) void*)g,
        (__attribute__((address_space(3))) void*)l, 16, 0, 0);
}

// level decomposition of a pixel index (0..8499) -> pair-space geometry
__device__ __forceinline__ void lvl_decomp(int pix, int& lb, int& y, int& x,
                                           int& rowp) {
    if (pix < 6400)      { y = pix / 80;            x = pix - y * 80;  rowp = 40; lb = 0; }
    else if (pix < 8000) { int r = pix - 6400; y = r / 40; x = r - y * 40; rowp = 20; lb = 3200; }
    else if (pix < 8400) { int r = pix - 8000; y = r / 20; x = r - y * 20; rowp = 10; lb = 4000; }
    else                 { int r = pix - 8400; y = r / 10; x = r - y * 10; rowp = 5;  lb = 4200; }
}

// ---------------------------------------------------------------------------
// Merged prep: blocks [0,8500) cast value, [8500,16900) cast query,
// [16900,17796) build BT (transposed bf16 weights, 896 rows x 256 k).
// ---------------------------------------------------------------------------
__global__ __launch_bounds__(256) void prep_all(
    const float* __restrict__ value, const float* __restrict__ query,
    const float* __restrict__ Wv, const float* __restrict__ Woff,
    const float* __restrict__ Wattn, const float* __restrict__ Wo,
    ushort_t* __restrict__ value_b, ushort_t* __restrict__ query_b,
    ushort_t* __restrict__ BT)
{
    const int bid = blockIdx.x;
    if (bid < 16900) {
        const float* src = (bid < 8500) ? value : query;
        ushort_t* dst = (bid < 8500) ? value_b : query_b;
        int i = (bid < 8500 ? bid : bid - 8500) * 256 + threadIdx.x;
        float4 f = ((const float4*)src)[i];
        ushort4 o;
        o.x = f2bf(f.x); o.y = f2bf(f.y); o.z = f2bf(f.z); o.w = f2bf(f.w);
        ((ushort4*)dst)[i] = o;
    } else {
        int idx = (bid - 16900) * 256 + threadIdx.x;   // 896*256
        int r = idx >> 8, k = idx & 255;
        float v;
        if (r < 256) v = Wv[k * 256 + r];
        else if (r < 640) {
            int n = r - 256;
            v = (n < 256) ? Woff[k * 256 + n] : Wattn[k * 128 + (n - 256)];
        } else v = Wo[k * 256 + (r - 640)];
        BT[idx] = f2bf(v);
    }
}

// ---------------------------------------------------------------------------
// Shared GEMM core (serial, proven): 128x128 tile, 4 waves, BK=64.
// Staging via global_load_lds dwordx4; XOR swizzle on the GLOBAL segment.
// ---------------------------------------------------------------------------
__device__ __forceinline__ void gemm_core(
    const ushort_t* __restrict__ A, const ushort_t* __restrict__ B, int M,
    int m0, int n0, ushort_t* Asl, ushort_t* Bsl, f32x4 acc[4][4])
{
    const int tid  = threadIdx.x;
    const int wave = tid >> 6, lane = tid & 63;
    const int quad = lane >> 4, mr = lane & 15;
    const int wm   = (wave >> 1) * 64, wn = (wave & 1) * 64;
    const int oct  = lane >> 3;       // 0..7 row-in-wave-slab
    const int bseg = lane & 7;        // physical 16B slot within row

    for (int k0 = 0; k0 < 256; k0 += 64) {
        __syncthreads();              // prior iteration's reads done
        #pragma unroll
        for (int i = 0; i < 4; i++) {
            int m  = i * 32 + wave * 8 + oct;          // block-relative row
            int gs = bseg ^ (m & 7);                   // swizzled source seg
            int am = min(m0 + m, M - 1);
            dma16(A + (size_t)am * 256 + k0 + gs * 8,
                  Asl + (size_t)(i * 32 + wave * 8) * 64 + lane * 8);
            int bn = n0 + m;
            dma16(B + (size_t)bn * 256 + k0 + gs * 8,
                  Bsl + (size_t)(i * 32 + wave * 8) * 64 + lane * 8);
        }
        __syncthreads();              // DMA landed
        #pragma unroll
        for (int ks = 0; ks < 2; ks++) {
            short8 af[4], bf[4];
            const int ksl = ks * 4 + quad;
            #pragma unroll
            for (int i = 0; i < 4; i++) {
                int m = wm + i * 16 + mr;
                af[i] = *(const short8*)&Asl[m * 64 + (ksl ^ (m & 7)) * 8];
                int n = wn + i * 16 + mr;
                bf[i] = *(const short8*)&Bsl[n * 64 + (ksl ^ (n & 7)) * 8];
            }
            #pragma unroll
            for (int i = 0; i < 4; i++)
                #pragma unroll
                for (int j = 0; j < 4; j++)
                    acc[i][j] = __builtin_amdgcn_mfma_f32_16x16x32_bf16(
                        af[i], bf[j], acc[i][j], 0, 0, 0);
        }
    }
}

// ---------------------------------------------------------------------------
// Fused GEMM1 (value->vperm f16 pair-interleaved x2 parity) + GEMM2
// (query->off/awl). LDS-repack epilogue (round-8 proven): acc staged into
// a swizzled 128x128 f16 LDS tile, then coalesced stores: mode1 row-major
// 16B; mode0 pair-major units + 2x128 boundary 2B scatters. Wrap pairs
// (never read by the sampler) skipped.
// ---------------------------------------------------------------------------
__global__ __launch_bounds__(256, 3) void gemm_fused(
    const ushort_t* __restrict__ Av, const ushort_t* __restrict__ Aq,
    const ushort_t* __restrict__ BT,
    const float* __restrict__ bv, const float* __restrict__ boff,
    const float* __restrict__ battn,
    ushort_t* __restrict__ vperm, ushort_t* __restrict__ off_b,
    ushort_t* __restrict__ awl_b)
{
    __shared__ ushort_t smem[16384];   // gemm: Asl|Bsl; epilogue: 128x128 f16
    ushort_t* Asl = smem;
    ushort_t* Bsl = smem + 8192;

    const int bid = blockIdx.x;
    int mode, m0, n0, M;
    const ushort_t *A, *B;
    if (bid < 532) { mode = 0; m0 = (bid >> 1) * 128; n0 = (bid & 1) * 128;
                     A = Av; B = BT; M = 34000; }
    else { int b2 = bid - 532;
           mode = 1; m0 = (b2 / 3) * 128; n0 = (b2 % 3) * 128;
           A = Aq; B = BT + 65536; M = 33600; }

    f32x4 acc[4][4];
    #pragma unroll
    for (int i = 0; i < 4; i++)
        #pragma unroll
        for (int j = 0; j < 4; j++) acc[i][j] = (f32x4){0.f, 0.f, 0.f, 0.f};

    gemm_core(A, B, M, m0, n0, Asl, Bsl, acc);

    const int tid  = threadIdx.x;
    const int wave = tid >> 6, lane = tid & 63;
    const int quad = lane >> 4, mr = lane & 15;
    const int wm   = (wave >> 1) * 64, wn = (wave & 1) * 64;

    // ---- step 1: acc (+bias, cvt) -> swizzled LDS tile ----
    __syncthreads();                   // last K-step's LDS reads done
    #pragma unroll
    for (int i = 0; i < 4; i++) {
        #pragma unroll
        for (int j = 0; j < 4; j++) {
            const int lc = wn + j * 16 + mr;
            const int c  = n0 + lc;
            const float bias = (mode == 0) ? bv[c]
                              : (c < 256 ? boff[c] : battn[c - 256]);
            #pragma unroll
            for (int reg = 0; reg < 4; reg++) {
                const int rl = wm + i * 16 + quad * 4 + reg;
                float val = acc[i][j][reg] + bias;
                ushort_t u;
                if (mode == 0) { union { _Float16 h; ushort_t u; } cv;
                                 cv.h = (_Float16)val; u = cv.u; }
                else u = f2bf(val);
                smem[rl * 128 + (lc ^ ((rl & 3) << 3))] = u;
            }
        }
    }
    __syncthreads();

    // ---- step 2: coalesced stores ----
    if (mode == 1) {
        for (int k = 0; k < 8; k++) {
            int sid = k * 256 + tid;            // 2048 x 16B
            int rl = sid >> 4, cc = (sid & 15) * 8;
            int row = m0 + rl;
            if (row >= M) continue;
            uint4 v = *(const uint4*)&smem[rl * 128 + (cc ^ ((rl & 3) << 3))];
            if (n0 < 256) *(uint4*)&off_b[(size_t)row * 256 + n0 + cc] = v;
            else          *(uint4*)&awl_b[(size_t)row * 128 + cc] = v;
        }
    } else {
        const int hb = n0 >> 5;                 // head base: 0 or 4
        // complete pairs: units 0..63 copy0 (t=2u), 64..126 copy1 (t=2u+1)
        for (int k = 0; k < 16; k++) {
            int sid = k * 256 + tid;            // 4096 slots, 127*32 used
            int unit = sid >> 5;
            if (unit >= 127) continue;
            int sub = sid & 31;
            int hh = sub >> 3, q = sub & 7;
            int copy = (unit >= 64) ? 1 : 0;
            int t = copy ? ((unit - 64) * 2 + 1) : (unit * 2);
            int row = m0 + t;
            if (row + 1 >= 34000) continue;     // need both pixels
            int b = row / LVTOT, pix = row - b * LVTOT;
            int lb, y, x, rowp;
            lvl_decomp(pix, lb, y, x, rowp);
            if (copy && x >= 2 * rowp - 1) continue;   // wrap pair: never read
            int p = x >> 1;                     // (x even: x/2) | (x odd: (x-1)/2)
            int pidx = copy * 4250 + lb + y * rowp + p;
            int h = hb + hh;
            uint2 a  = *(const uint2*)&smem[t * 128 +
                          ((hh * 32 + q * 4) ^ ((t & 3) << 3))];
            uint2 b2 = *(const uint2*)&smem[(t + 1) * 128 +
                          ((hh * 32 + q * 4) ^ (((t + 1) & 3) << 3))];
            uint4 o;
            o.x = (a.x & 0xffffu) | (b2.x << 16);
            o.y = (a.x >> 16)     | (b2.x & 0xffff0000u);
            o.z = (a.y & 0xffffu) | (b2.y << 16);
            o.w = (a.y >> 16)     | (b2.y & 0xffff0000u);
            *(uint4*)((char*)(vperm + (size_t)(b * NH + h) * PLANE_USH)
                      + (size_t)pidx * 128 + q * 16) = o;
        }
        // boundary scatters: pixel t=0 -> slot1 of left pair; t=127 -> slot0
        {
            int pixsel = tid >> 7;              // 0: t=0, 1: t=127
            int rem = tid & 127;
            int hh = rem >> 5, d = rem & 31;
            int t = pixsel ? 127 : 0;
            int row = m0 + t;
            if (row < 34000) {
                int b = row / LVTOT, pix = row - b * LVTOT;
                int lb, y, x, rowp;
                lvl_decomp(pix, lb, y, x, rowp);
                bool doit; int p, slot;
                if (!pixsel) { doit = (x >= 2);            p = (x - 2) >> 1; slot = 1; }
                else         { doit = (x < 2 * rowp - 1);  p = (x - 1) >> 1; slot = 0; }
                if (doit) {
                    int pidx = 4250 + lb + y * rowp + p;
                    int h = hb + hh;
                    vperm[(size_t)(b * NH + h) * PLANE_USH
                          + (size_t)pidx * 64 + d * 2 + slot] =
                        smem[t * 128 + ((hh * 32 + d) ^ ((t & 3) << 3))];
                }
            }
        }
    }
}

// ---------------------------------------------------------------------------
// GEMM3: sampled(bf16) @ Wo + bo -> out fp32. NEW epilogue: acc repacked
// through dead LDS in 4 chunks of 32 rows x 128 f32 (16 KB), quad-XOR
// swizzle (2-way aliasing = free), then float4 stores — 512 B contiguous
// per row segment, full 128 B lines (kills the 3.3x write amplification
// measured in r10: WRITE 114 MB vs 34.4 ideal, same store loop).
// ---------------------------------------------------------------------------
__global__ __launch_bounds__(256, 3) void gemm_out(
    const ushort_t* __restrict__ A, const ushort_t* __restrict__ BT,
    const float* __restrict__ bo, float* __restrict__ out)
{
    __shared__ ushort_t smem[16384];   // gemm: Asl|Bsl; epilogue: f32 chunks
    ushort_t* Asl = smem;
    ushort_t* Bsl = smem + 8192;

    const int m0 = (blockIdx.x >> 1) * 128;    // adjacency swizzle (263x2)
    const int n0 = (blockIdx.x & 1) * 128;
    const int M = 33600;

    f32x4 acc[4][4];
    #pragma unroll
    for (int i = 0; i < 4; i++)
        #pragma unroll
        for (int j = 0; j < 4; j++) acc[i][j] = (f32x4){0.f, 0.f, 0.f, 0.f};

    gemm_core(A, BT, M, m0, n0, Asl, Bsl, acc);

    const int tid  = threadIdx.x;
    const int wave = tid >> 6, lane = tid & 63;
    const int quad = lane >> 4, mr = lane & 15;
    const int half = wave >> 1;                // wm/64
    const int wn   = (wave & 1) * 64;
    float* fsm = (float*)smem;                 // 32 x 128 f32 = 16 KB

    #pragma unroll
    for (int i = 0; i < 4; i++) {
        __syncthreads();                       // prev chunk read / K-loop done
        #pragma unroll
        for (int j = 0; j < 4; j++) {
            const int lc = wn + j * 16 + mr;
            const float bias = bo[n0 + lc];
            #pragma unroll
            for (int reg = 0; reg < 4; reg++) {
                const int rloc = half * 16 + quad * 4 + reg;    // 0..31
                const int cs = lc ^ (quad << 4);                // bank spread
                fsm[rloc * 128 + cs] = acc[i][j][reg] + bias;
            }
        }
        __syncthreads();
        // 1024 float4 stores: 32 rows x 32 segs, 512 B contiguous per row
        #pragma unroll
        for (int k = 0; k < 4; k++) {
            int sid = k * 256 + tid;
            int rloc = sid >> 5, cw = (sid & 31) * 4;
            int row = m0 + (rloc >> 4) * 64 + i * 16 + (rloc & 15);
            if (row >= M) continue;
            int q2 = (rloc >> 2) & 3;
            float4 v = *(const float4*)&fsm[rloc * 128 + (cw ^ (q2 << 4))];
            *(float4*)&out[(size_t)row * 256 + n0 + cw] = v;
        }
    }
}

// ---------------------------------------------------------------------------
// Sampler v10 (unchanged, proven 47.9 µs): pair-interleaved gathers, plane-
// locality blocks (b, h, 32-query chunk), h = bid&7 XCD-pinned.
// ---------------------------------------------------------------------------
__global__ __launch_bounds__(256) void msda_sample(
    const ushort_t* __restrict__ vperm, const ushort_t* __restrict__ off,
    const ushort_t* __restrict__ awl, const float* __restrict__ refp,
    ushort_t* __restrict__ sampled)
{
    __shared__ int4 s_wi[16 * 33];   // (wt f16x2, wb f16x2, off_top, off_bot)

    const int tid = threadIdx.x;
    const int bid = blockIdx.x;
    const int h   = bid & 7;          // XCD-pinned head
    const int r   = bid >> 3;         // 0..1051
    const int b   = r / 263;
    const int c   = r - b * 263;      // chunk within batch
    const int q0b = c * 32;           // first query (within batch b)
    const size_t bq0 = (size_t)b * LQ + q0b;

    const int Hs[4]    = {80, 40, 20, 10};
    const int pbase[4] = {0, 3200, 4000, 4200};

    #pragma unroll
    for (int it = 0; it < 2; it++) {
        const int s  = it * 256 + tid;
        const int ql = s >> 4, lp = s & 15;
        const int l  = lp >> 2;
        const int qv = (q0b + ql < LQ) ? ql : 0;   // clamp tail chunk reads
        const size_t bq = bq0 + qv;
        const int Wl = Hs[l];

        unsigned od = *(const unsigned*)(off + bq * 256 + h * 32 + lp * 2);
        float ox = bflo(od), oy = bfhi(od);
        float lgt = bflo((unsigned)awl[bq * 128 + h * 16 + lp]);
        // softmax over the 16-lane (q) group, no max pass (bounded logits)
        float e = __expf(lgt);
        float sum = e;
        sum += __shfl_xor(sum, 1, 16);
        sum += __shfl_xor(sum, 2, 16);
        sum += __shfl_xor(sum, 4, 16);
        sum += __shfl_xor(sum, 8, 16);
        float aw = e * __builtin_amdgcn_rcpf(sum);

        float2 rp = *(const float2*)(refp + bq * 8 + l * 2);
        float x = rp.x * (float)Wl + ox - 0.5f;
        float y = rp.y * (float)Wl + oy - 0.5f;
        float x0f = floorf(x), y0f = floorf(y);
        float wx = x - x0f, wy = y - y0f;
        int x0 = (int)x0f, y0 = (int)y0f;
        float hx0 = ((x0 >= 0) & (x0 < Wl)) ? (1.f - wx) : 0.f;
        float hx1 = ((x0 + 1 >= 0) & (x0 + 1 < Wl)) ? wx : 0.f;
        float vy0w = ((y0 >= 0) & (y0 < Wl)) ? (1.f - wy) * aw : 0.f;
        float vy1w = ((y0 + 1 >= 0) & (y0 + 1 < Wl)) ? wy * aw : 0.f;
        // fold borders into a valid adjacent pair (px, px+1)
        int px = min(max(x0, 0), Wl - 2);
        float pl, pr;
        if (x0 < px)      { pl = hx1; pr = 0.f; }   // x0 left of grid
        else if (x0 > px) { pl = 0.f; pr = hx0; }   // x0 == Wl-1
        else              { pl = hx0; pr = hx1; }
        int cy0 = min(max(y0, 0), Wl - 1);
        int cy1 = min(max(y0 + 1, 0), Wl - 1);
        const int copy = px & 1;
        const int p    = copy ? ((px - 1) >> 1) : (px >> 1);
        const int rowp = Wl >> 1;
        const int cb   = copy * 4250 + pbase[l] + p;
        const int otop = (cb + cy0 * rowp) << 7;    // pair byte offsets
        const int obot = (cb + cy1 * rowp) << 7;
        unsigned wt = pk2u(__builtin_amdgcn_cvt_pkrtz(pl * vy0w, pr * vy0w));
        unsigned wb = pk2u(__builtin_amdgcn_cvt_pkrtz(pl * vy1w, pr * vy1w));
        s_wi[lp * 33 + ql] = make_int4((int)wt, (int)wb, otop, obot);
    }
    __syncthreads();

    const int ql  = tid >> 3;          // 0..31
    const int l8  = tid & 7;
    const int dby = l8 * 16;           // byte offset of this lane's 4-dim pair block

    if (q0b + ql < LQ) {
        const char* plane = (const char*)(vperm + (size_t)(b * NH + h) * PLANE_USH);
        float a0 = 0.f, a1 = 0.f, a2 = 0.f, a3 = 0.f;
        #pragma unroll
        for (int pt = 0; pt < 16; pt++) {
            int4 wi = s_wi[pt * 33 + ql];
            uint4 vt = *(const uint4*)(plane + (unsigned)(wi.z + dby));
            uint4 vb = *(const uint4*)(plane + (unsigned)(wi.w + dby));
            half2_t wt = ash2((unsigned)wi.x);
            half2_t wb = ash2((unsigned)wi.y);
            a0 = __builtin_amdgcn_fdot2(wt, ash2(vt.x), a0, false);
            a0 = __builtin_amdgcn_fdot2(wb, ash2(vb.x), a0, false);
            a1 = __builtin_amdgcn_fdot2(wt, ash2(vt.y), a1, false);
            a1 = __builtin_amdgcn_fdot2(wb, ash2(vb.y), a1, false);
            a2 = __builtin_amdgcn_fdot2(wt, ash2(vt.z), a2, false);
            a2 = __builtin_amdgcn_fdot2(wb, ash2(vb.z), a2, false);
            a3 = __builtin_amdgcn_fdot2(wt, ash2(vt.w), a3, false);
            a3 = __builtin_amdgcn_fdot2(wb, ash2(vb.w), a3, false);
        }
        const size_t bq = bq0 + ql;
        ushort4 o;
        o.x = f2bf(a0); o.y = f2bf(a1);
        o.z = f2bf(a2); o.w = f2bf(a3);
        *(ushort4*)(sampled + bq * 256 + h * 32 + l8 * 4) = o;
    }
}

extern "C" void kernel_launch(void* const* d_in, const int* in_sizes, int n_in,
                              void* d_out, int out_size, void* d_ws, size_t ws_size,
                              hipStream_t stream) {
    const float* query = (const float*)d_in[0];
    const float* refp  = (const float*)d_in[1];
    const float* value = (const float*)d_in[2];
    const float* Wv    = (const float*)d_in[4];
    const float* bv    = (const float*)d_in[5];
    const float* Woff  = (const float*)d_in[6];
    const float* boff  = (const float*)d_in[7];
    const float* Wattn = (const float*)d_in[8];
    const float* battn = (const float*)d_in[9];
    const float* Wo    = (const float*)d_in[10];
    const float* bo    = (const float*)d_in[11];
    float* out = (float*)d_out;

    // Workspace (95.7 MB): off 17.2 + awl 8.6 + value_b 17.4 + query_b 17.2
    //                      + vperm(pair x2) 34.8 + BT 0.46
    ushort_t* ws = (ushort_t*)d_ws;
    ushort_t* off_b   = ws;                       // 33600*256
    ushort_t* awl_b   = off_b + 8601600;          // 33600*128
    ushort_t* value_b = awl_b + 4300800;          // 34000*256
    ushort_t* query_b = value_b + 8704000;        // 33600*256 (aliased w/ sampled)
    ushort_t* vperm_b = query_b + 8601600;        // 32 planes * 544000 (f16 pairs)
    ushort_t* BT      = vperm_b + 17408000;       // 896*256
    ushort_t* sampled_b = query_b;                // alias: query dead after gemm_fused

    prep_all<<<dim3(17796), 256, 0, stream>>>(
        value, query, Wv, Woff, Wattn, Wo, value_b, query_b, BT);

    gemm_fused<<<dim3(532 + 789), 256, 0, stream>>>(
        value_b, query_b, BT, bv, boff, battn, vperm_b, off_b, awl_b);

    msda_sample<<<dim3(8 * 4 * 263), 256, 0, stream>>>(
        vperm_b, off_b, awl_b, refp, sampled_b);

    gemm_out<<<dim3(526), 256, 0, stream>>>(
        sampled_b, BT + 163840, bo, out);
}

// Round 12
// 209.531 us; speedup vs baseline: 1.3519x; 1.0163x over previous
//
#include <hip/hip_runtime.h>
#include <math.h>

#define BB 4
#define LQ 8400
#define NH 8
#define LVTOT 8500
#define HD 32
#define PLANE_USH 544000   // 8500 pairs x 64 ushorts (2 parity copies of 4250)

typedef __attribute__((ext_vector_type(8))) short short8;
typedef __attribute__((ext_vector_type(4))) float f32x4;
typedef __attribute__((ext_vector_type(2))) _Float16 half2_t;
typedef __attribute__((ext_vector_type(2))) __fp16 fp16x2_t;
typedef unsigned short ushort_t;

__device__ __forceinline__ ushort_t f2bf(float f) {
    union { float f; unsigned u; } v; v.f = f;
    unsigned r = v.u + 0x7fffu + ((v.u >> 16) & 1u);   // RNE
    return (ushort_t)(r >> 16);
}
__device__ __forceinline__ float bflo(unsigned u) {
    union { unsigned u; float f; } x; x.u = u << 16; return x.f;
}
__device__ __forceinline__ float bfhi(unsigned u) {
    union { unsigned u; float f; } x; x.u = u & 0xffff0000u; return x.f;
}
__device__ __forceinline__ half2_t ash2(unsigned u) {
    union { unsigned u; half2_t h; } x; x.u = u; return x.h;
}
__device__ __forceinline__ unsigned pk2u(fp16x2_t h) {
    union { fp16x2_t h; unsigned u; } x; x.h = h; return x.u;
}

// async global->LDS DMA, 16 B per lane (wave-uniform LDS base + lane*16)
__device__ __forceinline__ void dma16(const ushort_t* g, ushort_t* l) {
    __builtin_amdgcn_global_load_lds(
        (const __attribute__((address_space(1))) void*)g,
        (__attribute__((address_space(3))) void*)l, 16, 0, 0);
}

// level decomposition of a pixel index (0..8499) -> pair-space geometry
__device__ __forceinline__ void lvl_decomp(int pix, int& lb, int& y, int& x,
                                           int& rowp) {
    if (pix < 6400)      { y = pix / 80;            x = pix - y * 80;  rowp = 40; lb = 0; }
    else if (pix < 8000) { int r = pix - 6400; y = r / 40; x = r - y * 40; rowp = 20; lb = 3200; }
    else if (pix < 8400) { int r = pix - 8000; y = r / 20; x = r - y * 20; rowp = 10; lb = 4000; }
    else                 { int r = pix - 8400; y = r / 10; x = r - y * 10; rowp = 5;  lb = 4200; }
}

// ---------------------------------------------------------------------------
// Merged prep: blocks [0,8500) cast value, [8500,16900) cast query,
// [16900,17796) build BT (transposed bf16 weights, 896 rows x 256 k).
// ---------------------------------------------------------------------------
__global__ __launch_bounds__(256) void prep_all(
    const float* __restrict__ value, const float* __restrict__ query,
    const float* __restrict__ Wv, const float* __restrict__ Woff,
    const float* __restrict__ Wattn, const float* __restrict__ Wo,
    ushort_t* __restrict__ value_b, ushort_t* __restrict__ query_b,
    ushort_t* __restrict__ BT)
{
    const int bid = blockIdx.x;
    if (bid < 16900) {
        const float* src = (bid < 8500) ? value : query;
        ushort_t* dst = (bid < 8500) ? value_b : query_b;
        int i = (bid < 8500 ? bid : bid - 8500) * 256 + threadIdx.x;
        float4 f = ((const float4*)src)[i];
        ushort4 o;
        o.x = f2bf(f.x); o.y = f2bf(f.y); o.z = f2bf(f.z); o.w = f2bf(f.w);
        ((ushort4*)dst)[i] = o;
    } else {
        int idx = (bid - 16900) * 256 + threadIdx.x;   // 896*256
        int r = idx >> 8, k = idx & 255;
        float v;
        if (r < 256) v = Wv[k * 256 + r];
        else if (r < 640) {
            int n = r - 256;
            v = (n < 256) ? Woff[k * 256 + n] : Wattn[k * 128 + (n - 256)];
        } else v = Wo[k * 256 + (r - 640)];
        BT[idx] = f2bf(v);
    }
}

// ---------------------------------------------------------------------------
// GEMM core v5: 64x128 tile, 4 waves (2M x 2N, each wave 32x64), BK=64,
// serial proven 2-barrier loop. Halved BM doubles the block supply
// (gemm_fused 1321->2639 blocks, 10.3/CU) so the per-step vmcnt(0) drain is
// hidden by cross-block TLP (m114) — the diagnosed limiter at 2-5 blocks/CU.
// A-read multiplicity unchanged (= n-tile count) -> no extra HBM traffic.
// ---------------------------------------------------------------------------
__device__ __forceinline__ void gemm_core64(
    const ushort_t* __restrict__ A, const ushort_t* __restrict__ B, int M,
    int m0, int n0, ushort_t* Asl, ushort_t* Bsl, f32x4 acc[2][4])
{
    const int tid  = threadIdx.x;
    const int wave = tid >> 6, lane = tid & 63;
    const int quad = lane >> 4, mr = lane & 15;
    const int wm   = (wave >> 1) * 32, wn = (wave & 1) * 64;
    const int oct  = lane >> 3;       // 0..7 row-in-wave-slab
    const int bseg = lane & 7;        // physical 16B slot within row

    for (int k0 = 0; k0 < 256; k0 += 64) {
        __syncthreads();              // prior iteration's reads done
        #pragma unroll
        for (int i = 0; i < 2; i++) {                 // A: 64 rows
            int m  = i * 32 + wave * 8 + oct;
            int gs = bseg ^ (m & 7);
            int am = min(m0 + m, M - 1);
            dma16(A + (size_t)am * 256 + k0 + gs * 8,
                  Asl + (i * 32 + wave * 8) * 64 + lane * 8);
        }
        #pragma unroll
        for (int i = 0; i < 4; i++) {                 // B: 128 rows
            int n  = i * 32 + wave * 8 + oct;
            int gs = bseg ^ (n & 7);
            dma16(B + (size_t)(n0 + n) * 256 + k0 + gs * 8,
                  Bsl + (i * 32 + wave * 8) * 64 + lane * 8);
        }
        __syncthreads();              // DMA landed
        #pragma unroll
        for (int ks = 0; ks < 2; ks++) {
            short8 af[2], bf[4];
            const int ksl = ks * 4 + quad;
            #pragma unroll
            for (int i = 0; i < 2; i++) {
                int m = wm + i * 16 + mr;
                af[i] = *(const short8*)&Asl[m * 64 + (ksl ^ (m & 7)) * 8];
            }
            #pragma unroll
            for (int j = 0; j < 4; j++) {
                int n = wn + j * 16 + mr;
                bf[j] = *(const short8*)&Bsl[n * 64 + (ksl ^ (n & 7)) * 8];
            }
            #pragma unroll
            for (int i = 0; i < 2; i++)
                #pragma unroll
                for (int j = 0; j < 4; j++)
                    acc[i][j] = __builtin_amdgcn_mfma_f32_16x16x32_bf16(
                        af[i], bf[j], acc[i][j], 0, 0, 0);
        }
    }
}

// ---------------------------------------------------------------------------
// Fused GEMM1 (value->vperm f16 pair-interleaved x2 parity, 1064 blocks) +
// GEMM2 (query->off/awl, 1575 blocks). 64x128 tiles. LDS-repack epilogue:
// acc staged into a swizzled 64x128 f16 LDS tile, then coalesced stores:
// mode1 row-major 16B; mode0 pair-major units (32 copy0 + 31 copy1) +
// 2x128 boundary 2B scatters (t=0 slot1 / t=63 slot0). Wrap pairs skipped.
// Parity invariant: m0 % 64 == 0 and W even -> x parity == t parity.
// ---------------------------------------------------------------------------
__global__ __launch_bounds__(256, 4) void gemm_fused(
    const ushort_t* __restrict__ Av, const ushort_t* __restrict__ Aq,
    const ushort_t* __restrict__ BT,
    const float* __restrict__ bv, const float* __restrict__ boff,
    const float* __restrict__ battn,
    ushort_t* __restrict__ vperm, ushort_t* __restrict__ off_b,
    ushort_t* __restrict__ awl_b)
{
    __shared__ ushort_t smem[12288];   // A 64x64 | B 128x64; epi: 64x128 f16
    ushort_t* Asl = smem;
    ushort_t* Bsl = smem + 4096;

    const int bid = blockIdx.x;
    int mode, m0, n0, M;
    const ushort_t *A, *B;
    if (bid < 1064) { mode = 0; m0 = (bid >> 1) * 64; n0 = (bid & 1) * 128;
                      A = Av; B = BT; M = 34000; }
    else { int b2 = bid - 1064;
           mode = 1; m0 = (b2 / 3) * 64; n0 = (b2 % 3) * 128;
           A = Aq; B = BT + 65536; M = 33600; }

    f32x4 acc[2][4];
    #pragma unroll
    for (int i = 0; i < 2; i++)
        #pragma unroll
        for (int j = 0; j < 4; j++) acc[i][j] = (f32x4){0.f, 0.f, 0.f, 0.f};

    gemm_core64(A, B, M, m0, n0, Asl, Bsl, acc);

    const int tid  = threadIdx.x;
    const int wave = tid >> 6, lane = tid & 63;
    const int quad = lane >> 4, mr = lane & 15;
    const int wm   = (wave >> 1) * 32, wn = (wave & 1) * 64;

    // ---- step 1: acc (+bias, cvt) -> swizzled 64x128 LDS tile ----
    __syncthreads();                   // last K-step's LDS reads done
    #pragma unroll
    for (int i = 0; i < 2; i++) {
        #pragma unroll
        for (int j = 0; j < 4; j++) {
            const int lc = wn + j * 16 + mr;
            const int c  = n0 + lc;
            const float bias = (mode == 0) ? bv[c]
                              : (c < 256 ? boff[c] : battn[c - 256]);
            #pragma unroll
            for (int reg = 0; reg < 4; reg++) {
                const int rl = wm + i * 16 + quad * 4 + reg;   // 0..63
                float val = acc[i][j][reg] + bias;
                ushort_t u;
                if (mode == 0) { union { _Float16 h; ushort_t u; } cv;
                                 cv.h = (_Float16)val; u = cv.u; }
                else u = f2bf(val);
                smem[rl * 128 + (lc ^ ((rl & 3) << 3))] = u;
            }
        }
    }
    __syncthreads();

    // ---- step 2: coalesced stores ----
    if (mode == 1) {
        #pragma unroll
        for (int k = 0; k < 4; k++) {
            int sid = k * 256 + tid;            // 1024 x 16B
            int rl = sid >> 4, cc = (sid & 15) * 8;
            int row = m0 + rl;
            if (row >= M) continue;
            uint4 v = *(const uint4*)&smem[rl * 128 + (cc ^ ((rl & 3) << 3))];
            if (n0 < 256) *(uint4*)&off_b[(size_t)row * 256 + n0 + cc] = v;
            else          *(uint4*)&awl_b[(size_t)row * 128 + cc] = v;
        }
    } else {
        const int hb = n0 >> 5;                 // head base: 0 or 4
        // complete pairs: units 0..31 copy0 (t=2u), 32..62 copy1 (t=2u+1)
        #pragma unroll
        for (int k = 0; k < 8; k++) {
            int sid = k * 256 + tid;            // 2048 slots, 63*32 used
            int unit = sid >> 5;
            if (unit >= 63) continue;
            int sub = sid & 31;
            int hh = sub >> 3, q = sub & 7;
            int copy = (unit >= 32) ? 1 : 0;
            int t = copy ? ((unit - 32) * 2 + 1) : (unit * 2);
            int row = m0 + t;
            if (row + 1 >= 34000) continue;     // need both pixels
            int b = row / LVTOT, pix = row - b * LVTOT;
            int lb, y, x, rowp;
            lvl_decomp(pix, lb, y, x, rowp);
            if (copy && x >= 2 * rowp - 1) continue;   // wrap pair: never read
            int p = x >> 1;                     // (x even: x/2) | (x odd: (x-1)/2)
            int pidx = copy * 4250 + lb + y * rowp + p;
            int h = hb + hh;
            uint2 a  = *(const uint2*)&smem[t * 128 +
                          ((hh * 32 + q * 4) ^ ((t & 3) << 3))];
            uint2 b2 = *(const uint2*)&smem[(t + 1) * 128 +
                          ((hh * 32 + q * 4) ^ (((t + 1) & 3) << 3))];
            uint4 o;
            o.x = (a.x & 0xffffu) | (b2.x << 16);
            o.y = (a.x >> 16)     | (b2.x & 0xffff0000u);
            o.z = (a.y & 0xffffu) | (b2.y << 16);
            o.w = (a.y >> 16)     | (b2.y & 0xffff0000u);
            *(uint4*)((char*)(vperm + (size_t)(b * NH + h) * PLANE_USH)
                      + (size_t)pidx * 128 + q * 16) = o;
        }
        // boundary scatters: pixel t=0 -> slot1 of left pair; t=63 -> slot0
        {
            int pixsel = tid >> 7;              // 0: t=0, 1: t=63
            int rem = tid & 127;
            int hh = rem >> 5, d = rem & 31;
            int t = pixsel ? 63 : 0;
            int row = m0 + t;
            if (row < 34000) {
                int b = row / LVTOT, pix = row - b * LVTOT;
                int lb, y, x, rowp;
                lvl_decomp(pix, lb, y, x, rowp);
                bool doit; int p, slot;
                if (!pixsel) { doit = (x >= 2);            p = (x - 2) >> 1; slot = 1; }
                else         { doit = (x < 2 * rowp - 1);  p = (x - 1) >> 1; slot = 0; }
                if (doit) {
                    int pidx = 4250 + lb + y * rowp + p;
                    int h = hb + hh;
                    vperm[(size_t)(b * NH + h) * PLANE_USH
                          + (size_t)pidx * 64 + d * 2 + slot] =
                        smem[t * 128 + ((hh * 32 + d) ^ ((t & 3) << 3))];
                }
            }
        }
    }
}

// ---------------------------------------------------------------------------
// GEMM3: sampled(bf16) @ Wo + bo -> out fp32. 64x128 tiles (1050 blocks),
// LDS-repack epilogue (r11 proven): 2 chunks of 32 rows x 128 f32, quad-XOR
// swizzle, float4 stores — full 128 B lines.
// ---------------------------------------------------------------------------
__global__ __launch_bounds__(256, 4) void gemm_out(
    const ushort_t* __restrict__ A, const ushort_t* __restrict__ BT,
    const float* __restrict__ bo, float* __restrict__ out)
{
    __shared__ ushort_t smem[12288];   // A|B stage; epi: 32x128 f32 chunks
    ushort_t* Asl = smem;
    ushort_t* Bsl = smem + 4096;

    const int m0 = (blockIdx.x >> 1) * 64;     // adjacency swizzle (525x2)
    const int n0 = (blockIdx.x & 1) * 128;
    const int M = 33600;

    f32x4 acc[2][4];
    #pragma unroll
    for (int i = 0; i < 2; i++)
        #pragma unroll
        for (int j = 0; j < 4; j++) acc[i][j] = (f32x4){0.f, 0.f, 0.f, 0.f};

    gemm_core64(A, BT, M, m0, n0, Asl, Bsl, acc);

    const int tid  = threadIdx.x;
    const int wave = tid >> 6, lane = tid & 63;
    const int quad = lane >> 4, mr = lane & 15;
    const int half = wave >> 1;
    const int wn   = (wave & 1) * 64;
    float* fsm = (float*)smem;                 // 32 x 128 f32 = 16 KB

    #pragma unroll
    for (int i = 0; i < 2; i++) {
        __syncthreads();                       // prev chunk read / K-loop done
        #pragma unroll
        for (int j = 0; j < 4; j++) {
            const int lc = wn + j * 16 + mr;
            const float bias = bo[n0 + lc];
            #pragma unroll
            for (int reg = 0; reg < 4; reg++) {
                const int rloc = half * 16 + quad * 4 + reg;    // 0..31
                const int cs = lc ^ (quad << 4);                // bank spread
                fsm[rloc * 128 + cs] = acc[i][j][reg] + bias;
            }
        }
        __syncthreads();
        // 1024 float4 stores: 32 rows x 32 segs, 512 B contiguous per row
        #pragma unroll
        for (int k = 0; k < 4; k++) {
            int sid = k * 256 + tid;
            int rloc = sid >> 5, cw = (sid & 31) * 4;
            int row = m0 + (rloc >> 4) * 32 + i * 16 + (rloc & 15);
            if (row >= M) continue;
            int q2 = (rloc >> 2) & 3;
            float4 v = *(const float4*)&fsm[rloc * 128 + (cw ^ (q2 << 4))];
            *(float4*)&out[(size_t)row * 256 + n0 + cw] = v;
        }
    }
}

// ---------------------------------------------------------------------------
// Sampler v10 (unchanged, proven 47.8 µs): pair-interleaved gathers, plane-
// locality blocks (b, h, 32-query chunk), h = bid&7 XCD-pinned.
// ---------------------------------------------------------------------------
__global__ __launch_bounds__(256) void msda_sample(
    const ushort_t* __restrict__ vperm, const ushort_t* __restrict__ off,
    const ushort_t* __restrict__ awl, const float* __restrict__ refp,
    ushort_t* __restrict__ sampled)
{
    __shared__ int4 s_wi[16 * 33];   // (wt f16x2, wb f16x2, off_top, off_bot)

    const int tid = threadIdx.x;
    const int bid = blockIdx.x;
    const int h   = bid & 7;          // XCD-pinned head
    const int r   = bid >> 3;         // 0..1051
    const int b   = r / 263;
    const int c   = r - b * 263;      // chunk within batch
    const int q0b = c * 32;           // first query (within batch b)
    const size_t bq0 = (size_t)b * LQ + q0b;

    const int Hs[4]    = {80, 40, 20, 10};
    const int pbase[4] = {0, 3200, 4000, 4200};

    #pragma unroll
    for (int it = 0; it < 2; it++) {
        const int s  = it * 256 + tid;
        const int ql = s >> 4, lp = s & 15;
        const int l  = lp >> 2;
        const int qv = (q0b + ql < LQ) ? ql : 0;   // clamp tail chunk reads
        const size_t bq = bq0 + qv;
        const int Wl = Hs[l];

        unsigned od = *(const unsigned*)(off + bq * 256 + h * 32 + lp * 2);
        float ox = bflo(od), oy = bfhi(od);
        float lgt = bflo((unsigned)awl[bq * 128 + h * 16 + lp]);
        // softmax over the 16-lane (q) group, no max pass (bounded logits)
        float e = __expf(lgt);
        float sum = e;
        sum += __shfl_xor(sum, 1, 16);
        sum += __shfl_xor(sum, 2, 16);
        sum += __shfl_xor(sum, 4, 16);
        sum += __shfl_xor(sum, 8, 16);
        float aw = e * __builtin_amdgcn_rcpf(sum);

        float2 rp = *(const float2*)(refp + bq * 8 + l * 2);
        float x = rp.x * (float)Wl + ox - 0.5f;
        float y = rp.y * (float)Wl + oy - 0.5f;
        float x0f = floorf(x), y0f = floorf(y);
        float wx = x - x0f, wy = y - y0f;
        int x0 = (int)x0f, y0 = (int)y0f;
        float hx0 = ((x0 >= 0) & (x0 < Wl)) ? (1.f - wx) : 0.f;
        float hx1 = ((x0 + 1 >= 0) & (x0 + 1 < Wl)) ? wx : 0.f;
        float vy0w = ((y0 >= 0) & (y0 < Wl)) ? (1.f - wy) * aw : 0.f;
        float vy1w = ((y0 + 1 >= 0) & (y0 + 1 < Wl)) ? wy * aw : 0.f;
        // fold borders into a valid adjacent pair (px, px+1)
        int px = min(max(x0, 0), Wl - 2);
        float pl, pr;
        if (x0 < px)      { pl = hx1; pr = 0.f; }   // x0 left of grid
        else if (x0 > px) { pl = 0.f; pr = hx0; }   // x0 == Wl-1
        else              { pl = hx0; pr = hx1; }
        int cy0 = min(max(y0, 0), Wl - 1);
        int cy1 = min(max(y0 + 1, 0), Wl - 1);
        const int copy = px & 1;
        const int p    = copy ? ((px - 1) >> 1) : (px >> 1);
        const int rowp = Wl >> 1;
        const int cb   = copy * 4250 + pbase[l] + p;
        const int otop = (cb + cy0 * rowp) << 7;    // pair byte offsets
        const int obot = (cb + cy1 * rowp) << 7;
        unsigned wt = pk2u(__builtin_amdgcn_cvt_pkrtz(pl * vy0w, pr * vy0w));
        unsigned wb = pk2u(__builtin_amdgcn_cvt_pkrtz(pl * vy1w, pr * vy1w));
        s_wi[lp * 33 + ql] = make_int4((int)wt, (int)wb, otop, obot);
    }
    __syncthreads();

    const int ql  = tid >> 3;          // 0..31
    const int l8  = tid & 7;
    const int dby = l8 * 16;           // byte offset of this lane's 4-dim pair block

    if (q0b + ql < LQ) {
        const char* plane = (const char*)(vperm + (size_t)(b * NH + h) * PLANE_USH);
        float a0 = 0.f, a1 = 0.f, a2 = 0.f, a3 = 0.f;
        #pragma unroll
        for (int pt = 0; pt < 16; pt++) {
            int4 wi = s_wi[pt * 33 + ql];
            uint4 vt = *(const uint4*)(plane + (unsigned)(wi.z + dby));
            uint4 vb = *(const uint4*)(plane + (unsigned)(wi.w + dby));
            half2_t wt = ash2((unsigned)wi.x);
            half2_t wb = ash2((unsigned)wi.y);
            a0 = __builtin_amdgcn_fdot2(wt, ash2(vt.x), a0, false);
            a0 = __builtin_amdgcn_fdot2(wb, ash2(vb.x), a0, false);
            a1 = __builtin_amdgcn_fdot2(wt, ash2(vt.y), a1, false);
            a1 = __builtin_amdgcn_fdot2(wb, ash2(vb.y), a1, false);
            a2 = __builtin_amdgcn_fdot2(wt, ash2(vt.z), a2, false);
            a2 = __builtin_amdgcn_fdot2(wb, ash2(vb.z), a2, false);
            a3 = __builtin_amdgcn_fdot2(wt, ash2(vt.w), a3, false);
            a3 = __builtin_amdgcn_fdot2(wb, ash2(vb.w), a3, false);
        }
        const size_t bq = bq0 + ql;
        ushort4 o;
        o.x = f2bf(a0); o.y = f2bf(a1);
        o.z = f2bf(a2); o.w = f2bf(a3);
        *(ushort4*)(sampled + bq * 256 + h * 32 + l8 * 4) = o;
    }
}

extern "C" void kernel_launch(void* const* d_in, const int* in_sizes, int n_in,
                              void* d_out, int out_size, void* d_ws, size_t ws_size,
                              hipStream_t stream) {
    const float* query = (const float*)d_in[0];
    const float* refp  = (const float*)d_in[1];
    const float* value = (const float*)d_in[2];
    const float* Wv    = (const float*)d_in[4];
    const float* bv    = (const float*)d_in[5];
    const float* Woff  = (const float*)d_in[6];
    const float* boff  = (const float*)d_in[7];
    const float* Wattn = (const float*)d_in[8];
    const float* battn = (const float*)d_in[9];
    const float* Wo    = (const float*)d_in[10];
    const float* bo    = (const float*)d_in[11];
    float* out = (float*)d_out;

    // Workspace (95.7 MB): off 17.2 + awl 8.6 + value_b 17.4 + query_b 17.2
    //                      + vperm(pair x2) 34.8 + BT 0.46
    ushort_t* ws = (ushort_t*)d_ws;
    ushort_t* off_b   = ws;                       // 33600*256
    ushort_t* awl_b   = off_b + 8601600;          // 33600*128
    ushort_t* value_b = awl_b + 4300800;          // 34000*256
    ushort_t* query_b = value_b + 8704000;        // 33600*256 (aliased w/ sampled)
    ushort_t* vperm_b = query_b + 8601600;        // 32 planes * 544000 (f16 pairs)
    ushort_t* BT      = vperm_b + 17408000;       // 896*256
    ushort_t* sampled_b = query_b;                // alias: query dead after gemm_fused

    prep_all<<<dim3(17796), 256, 0, stream>>>(
        value, query, Wv, Woff, Wattn, Wo, value_b, query_b, BT);

    gemm_fused<<<dim3(1064 + 1575), 256, 0, stream>>>(
        value_b, query_b, BT, bv, boff, battn, vperm_b, off_b, awl_b);

    msda_sample<<<dim3(8 * 4 * 263), 256, 0, stream>>>(
        vperm_b, off_b, awl_b, refp, sampled_b);

    gemm_out<<<dim3(1050), 256, 0, stream>>>(
        sampled_b, BT + 163840, bo, out);
}

// Round 13
// 207.093 us; speedup vs baseline: 1.3679x; 1.0118x over previous
//
#include <hip/hip_runtime.h>
#include <math.h>

#define BB 4
#define LQ 8400
#define NH 8
#define LVTOT 8500
#define HD 32
#define PLANE_USH 544000   // 8500 pairs x 64 ushorts (2 parity copies of 4250)

typedef __attribute__((ext_vector_type(8))) short short8;
typedef __attribute__((ext_vector_type(4))) float f32x4;
typedef __attribute__((ext_vector_type(2))) _Float16 half2_t;
typedef __attribute__((ext_vector_type(2))) __fp16 fp16x2_t;
typedef unsigned short ushort_t;

__device__ __forceinline__ ushort_t f2bf(float f) {
    union { float f; unsigned u; } v; v.f = f;
    unsigned r = v.u + 0x7fffu + ((v.u >> 16) & 1u);   // RNE
    return (ushort_t)(r >> 16);
}
__device__ __forceinline__ float bflo(unsigned u) {
    union { unsigned u; float f; } x; x.u = u << 16; return x.f;
}
__device__ __forceinline__ float bfhi(unsigned u) {
    union { unsigned u; float f; } x; x.u = u & 0xffff0000u; return x.f;
}
__device__ __forceinline__ half2_t ash2(unsigned u) {
    union { unsigned u; half2_t h; } x; x.u = u; return x.h;
}
__device__ __forceinline__ unsigned pk2u(fp16x2_t h) {
    union { fp16x2_t h; unsigned u; } x; x.h = h; return x.u;
}

// async global->LDS DMA, 16 B per lane (wave-uniform LDS base + lane*16)
__device__ __forceinline__ void dma16(const ushort_t* g, ushort_t* l) {
    __builtin_amdgcn_global_load_lds(
        (const __attribute__((address_space(1))) void*)g,
        (__attribute__((address_space(3))) void*)l, 16, 0, 0);
}
__device__ __forceinline__ void dma16g(const void* g, void* l) {
    __builtin_amdgcn_global_load_lds(
        (const __attribute__((address_space(1))) void*)g,
        (__attribute__((address_space(3))) void*)l, 16, 0, 0);
}

// level decomposition of a pixel index (0..8499) -> pair-space geometry
__device__ __forceinline__ void lvl_decomp(int pix, int& lb, int& y, int& x,
                                           int& rowp) {
    if (pix < 6400)      { y = pix / 80;            x = pix - y * 80;  rowp = 40; lb = 0; }
    else if (pix < 8000) { int r = pix - 6400; y = r / 40; x = r - y * 40; rowp = 20; lb = 3200; }
    else if (pix < 8400) { int r = pix - 8000; y = r / 20; x = r - y * 20; rowp = 10; lb = 4000; }
    else                 { int r = pix - 8400; y = r / 10; x = r - y * 10; rowp = 5;  lb = 4200; }
}

// ---------------------------------------------------------------------------
// prep_bt: BT build only (896 blocks). Value/query casting is now fused
// into gemm_fused's f32-A staging path — prep's 104 MB of cast traffic gone.
// ---------------------------------------------------------------------------
__global__ __launch_bounds__(256) void prep_bt(
    const float* __restrict__ Wv, const float* __restrict__ Woff,
    const float* __restrict__ Wattn, const float* __restrict__ Wo,
    ushort_t* __restrict__ BT)
{
    int idx = blockIdx.x * 256 + threadIdx.x;   // 896*256
    int r = idx >> 8, k = idx & 255;
    float v;
    if (r < 256) v = Wv[k * 256 + r];
    else if (r < 640) {
        int n = r - 256;
        v = (n < 256) ? Woff[k * 256 + n] : Wattn[k * 128 + (n - 256)];
    } else v = Wo[k * 256 + (r - 640)];
    BT[idx] = f2bf(v);
}

// ---------------------------------------------------------------------------
// GEMM core v6 (f32-A): 64x128 tile, 4 waves (2M x 2N), BK=64, serial
// 2-barrier loop. A staged as f32 (64 rows x 256 B/step, 16-seg XOR swizzle
// seg^(m&15)); fragments converted in-register with the bit-identical f2bf
// (results unchanged vs pre-cast bf16). B staged bf16 from BT as proven.
// ---------------------------------------------------------------------------
__device__ __forceinline__ void gemm_core64_f32a(
    const float* __restrict__ A, const ushort_t* __restrict__ B, int M,
    int m0, int n0, float* Af, ushort_t* Bsl, f32x4 acc[2][4])
{
    const int tid  = threadIdx.x;
    const int wave = tid >> 6, lane = tid & 63;
    const int quad = lane >> 4, mr = lane & 15;
    const int wm   = (wave >> 1) * 32, wn = (wave & 1) * 64;
    const int oct  = lane >> 3;       // B path: 8 rows/slab
    const int bseg = lane & 7;
    const int r4   = lane >> 4;       // A path: 4 rows/slab
    const int s16  = lane & 15;       // 16 x 16B segs per 256 B row

    for (int k0 = 0; k0 < 256; k0 += 64) {
        __syncthreads();              // prior iteration's reads done
        // A: 64 rows x 64 floats, 4 passes x 16 rows
        #pragma unroll
        for (int i = 0; i < 4; i++) {
            int m  = i * 16 + wave * 4 + r4;
            int gs = s16 ^ (m & 15);                   // swizzled source seg
            int am = min(m0 + m, M - 1);
            dma16g((const char*)A + (size_t)am * 1024 + (size_t)(k0 + gs * 4) * 4,
                   (char*)Af + (i * 16 + wave * 4) * 256 + lane * 16);
        }
        // B: 128 rows bf16, 4 passes x 32 rows
        #pragma unroll
        for (int i = 0; i < 4; i++) {
            int n  = i * 32 + wave * 8 + oct;
            int gs = bseg ^ (n & 7);
            dma16(B + (size_t)(n0 + n) * 256 + k0 + gs * 8,
                  Bsl + (i * 32 + wave * 8) * 64 + lane * 8);
        }
        __syncthreads();              // DMA landed
        #pragma unroll
        for (int ks = 0; ks < 2; ks++) {
            short8 af[2], bf[4];
            const int ksl = ks * 4 + quad;
            #pragma unroll
            for (int i = 0; i < 2; i++) {
                int m  = wm + i * 16 + mr;
                int p0 = (ksl * 2) ^ (m & 15);
                int p1 = (ksl * 2 + 1) ^ (m & 15);
                float4 lo = *(const float4*)&Af[m * 64 + p0 * 4];
                float4 hi = *(const float4*)&Af[m * 64 + p1 * 4];
                short8 a;
                a[0] = (short)f2bf(lo.x); a[1] = (short)f2bf(lo.y);
                a[2] = (short)f2bf(lo.z); a[3] = (short)f2bf(lo.w);
                a[4] = (short)f2bf(hi.x); a[5] = (short)f2bf(hi.y);
                a[6] = (short)f2bf(hi.z); a[7] = (short)f2bf(hi.w);
                af[i] = a;
            }
            #pragma unroll
            for (int j = 0; j < 4; j++) {
                int n = wn + j * 16 + mr;
                bf[j] = *(const short8*)&Bsl[n * 64 + (ksl ^ (n & 7)) * 8];
            }
            #pragma unroll
            for (int i = 0; i < 2; i++)
                #pragma unroll
                for (int j = 0; j < 4; j++)
                    acc[i][j] = __builtin_amdgcn_mfma_f32_16x16x32_bf16(
                        af[i], bf[j], acc[i][j], 0, 0, 0);
        }
    }
}

// ---------------------------------------------------------------------------
// GEMM core v5 (bf16-A, proven r12): used by gemm_out (A = sampled bf16).
// ---------------------------------------------------------------------------
__device__ __forceinline__ void gemm_core64(
    const ushort_t* __restrict__ A, const ushort_t* __restrict__ B, int M,
    int m0, int n0, ushort_t* Asl, ushort_t* Bsl, f32x4 acc[2][4])
{
    const int tid  = threadIdx.x;
    const int wave = tid >> 6, lane = tid & 63;
    const int quad = lane >> 4, mr = lane & 15;
    const int wm   = (wave >> 1) * 32, wn = (wave & 1) * 64;
    const int oct  = lane >> 3;
    const int bseg = lane & 7;

    for (int k0 = 0; k0 < 256; k0 += 64) {
        __syncthreads();
        #pragma unroll
        for (int i = 0; i < 2; i++) {                 // A: 64 rows
            int m  = i * 32 + wave * 8 + oct;
            int gs = bseg ^ (m & 7);
            int am = min(m0 + m, M - 1);
            dma16(A + (size_t)am * 256 + k0 + gs * 8,
                  Asl + (i * 32 + wave * 8) * 64 + lane * 8);
        }
        #pragma unroll
        for (int i = 0; i < 4; i++) {                 // B: 128 rows
            int n  = i * 32 + wave * 8 + oct;
            int gs = bseg ^ (n & 7);
            dma16(B + (size_t)(n0 + n) * 256 + k0 + gs * 8,
                  Bsl + (i * 32 + wave * 8) * 64 + lane * 8);
        }
        __syncthreads();
        #pragma unroll
        for (int ks = 0; ks < 2; ks++) {
            short8 af[2], bf[4];
            const int ksl = ks * 4 + quad;
            #pragma unroll
            for (int i = 0; i < 2; i++) {
                int m = wm + i * 16 + mr;
                af[i] = *(const short8*)&Asl[m * 64 + (ksl ^ (m & 7)) * 8];
            }
            #pragma unroll
            for (int j = 0; j < 4; j++) {
                int n = wn + j * 16 + mr;
                bf[j] = *(const short8*)&Bsl[n * 64 + (ksl ^ (n & 7)) * 8];
            }
            #pragma unroll
            for (int i = 0; i < 2; i++)
                #pragma unroll
                for (int j = 0; j < 4; j++)
                    acc[i][j] = __builtin_amdgcn_mfma_f32_16x16x32_bf16(
                        af[i], bf[j], acc[i][j], 0, 0, 0);
        }
    }
}

// ---------------------------------------------------------------------------
// Fused GEMM1 (value f32 ->vperm f16 pair-interleaved x2 parity, 1064
// blocks) + GEMM2 (query f32 ->off/awl, 1575 blocks). 64x128 tiles, f32-A
// core. LDS-repack epilogue (r12 proven).
// ---------------------------------------------------------------------------
__global__ __launch_bounds__(256, 4) void gemm_fused(
    const float* __restrict__ Av, const float* __restrict__ Aq,
    const ushort_t* __restrict__ BT,
    const float* __restrict__ bv, const float* __restrict__ boff,
    const float* __restrict__ battn,
    ushort_t* __restrict__ vperm, ushort_t* __restrict__ off_b,
    ushort_t* __restrict__ awl_b)
{
    __shared__ ushort_t smem[16384];   // A f32 16KB | B bf16 16KB; epi: 64x128 f16
    float*    Af  = (float*)smem;      // 4096 floats
    ushort_t* Bsl = smem + 8192;

    const int bid = blockIdx.x;
    int mode, m0, n0, M;
    const float* A;
    const ushort_t* B;
    if (bid < 1064) { mode = 0; m0 = (bid >> 1) * 64; n0 = (bid & 1) * 128;
                      A = Av; B = BT; M = 34000; }
    else { int b2 = bid - 1064;
           mode = 1; m0 = (b2 / 3) * 64; n0 = (b2 % 3) * 128;
           A = Aq; B = BT + 65536; M = 33600; }

    f32x4 acc[2][4];
    #pragma unroll
    for (int i = 0; i < 2; i++)
        #pragma unroll
        for (int j = 0; j < 4; j++) acc[i][j] = (f32x4){0.f, 0.f, 0.f, 0.f};

    gemm_core64_f32a(A, B, M, m0, n0, Af, Bsl, acc);

    const int tid  = threadIdx.x;
    const int wave = tid >> 6, lane = tid & 63;
    const int quad = lane >> 4, mr = lane & 15;
    const int wm   = (wave >> 1) * 32, wn = (wave & 1) * 64;

    // ---- step 1: acc (+bias, cvt) -> swizzled 64x128 LDS tile ----
    __syncthreads();                   // last K-step's LDS reads done
    #pragma unroll
    for (int i = 0; i < 2; i++) {
        #pragma unroll
        for (int j = 0; j < 4; j++) {
            const int lc = wn + j * 16 + mr;
            const int c  = n0 + lc;
            const float bias = (mode == 0) ? bv[c]
                              : (c < 256 ? boff[c] : battn[c - 256]);
            #pragma unroll
            for (int reg = 0; reg < 4; reg++) {
                const int rl = wm + i * 16 + quad * 4 + reg;   // 0..63
                float val = acc[i][j][reg] + bias;
                ushort_t u;
                if (mode == 0) { union { _Float16 h; ushort_t u; } cv;
                                 cv.h = (_Float16)val; u = cv.u; }
                else u = f2bf(val);
                smem[rl * 128 + (lc ^ ((rl & 3) << 3))] = u;
            }
        }
    }
    __syncthreads();

    // ---- step 2: coalesced stores ----
    if (mode == 1) {
        #pragma unroll
        for (int k = 0; k < 4; k++) {
            int sid = k * 256 + tid;            // 1024 x 16B
            int rl = sid >> 4, cc = (sid & 15) * 8;
            int row = m0 + rl;
            if (row >= M) continue;
            uint4 v = *(const uint4*)&smem[rl * 128 + (cc ^ ((rl & 3) << 3))];
            if (n0 < 256) *(uint4*)&off_b[(size_t)row * 256 + n0 + cc] = v;
            else          *(uint4*)&awl_b[(size_t)row * 128 + cc] = v;
        }
    } else {
        const int hb = n0 >> 5;                 // head base: 0 or 4
        // complete pairs: units 0..31 copy0 (t=2u), 32..62 copy1 (t=2u+1)
        #pragma unroll
        for (int k = 0; k < 8; k++) {
            int sid = k * 256 + tid;            // 2048 slots, 63*32 used
            int unit = sid >> 5;
            if (unit >= 63) continue;
            int sub = sid & 31;
            int hh = sub >> 3, q = sub & 7;
            int copy = (unit >= 32) ? 1 : 0;
            int t = copy ? ((unit - 32) * 2 + 1) : (unit * 2);
            int row = m0 + t;
            if (row + 1 >= 34000) continue;     // need both pixels
            int b = row / LVTOT, pix = row - b * LVTOT;
            int lb, y, x, rowp;
            lvl_decomp(pix, lb, y, x, rowp);
            if (copy && x >= 2 * rowp - 1) continue;   // wrap pair: never read
            int p = x >> 1;
            int pidx = copy * 4250 + lb + y * rowp + p;
            int h = hb + hh;
            uint2 a  = *(const uint2*)&smem[t * 128 +
                          ((hh * 32 + q * 4) ^ ((t & 3) << 3))];
            uint2 b2 = *(const uint2*)&smem[(t + 1) * 128 +
                          ((hh * 32 + q * 4) ^ (((t + 1) & 3) << 3))];
            uint4 o;
            o.x = (a.x & 0xffffu) | (b2.x << 16);
            o.y = (a.x >> 16)     | (b2.x & 0xffff0000u);
            o.z = (a.y & 0xffffu) | (b2.y << 16);
            o.w = (a.y >> 16)     | (b2.y & 0xffff0000u);
            *(uint4*)((char*)(vperm + (size_t)(b * NH + h) * PLANE_USH)
                      + (size_t)pidx * 128 + q * 16) = o;
        }
        // boundary scatters: pixel t=0 -> slot1 of left pair; t=63 -> slot0
        {
            int pixsel = tid >> 7;              // 0: t=0, 1: t=63
            int rem = tid & 127;
            int hh = rem >> 5, d = rem & 31;
            int t = pixsel ? 63 : 0;
            int row = m0 + t;
            if (row < 34000) {
                int b = row / LVTOT, pix = row - b * LVTOT;
                int lb, y, x, rowp;
                lvl_decomp(pix, lb, y, x, rowp);
                bool doit; int p, slot;
                if (!pixsel) { doit = (x >= 2);            p = (x - 2) >> 1; slot = 1; }
                else         { doit = (x < 2 * rowp - 1);  p = (x - 1) >> 1; slot = 0; }
                if (doit) {
                    int pidx = 4250 + lb + y * rowp + p;
                    int h = hb + hh;
                    vperm[(size_t)(b * NH + h) * PLANE_USH
                          + (size_t)pidx * 64 + d * 2 + slot] =
                        smem[t * 128 + ((hh * 32 + d) ^ ((t & 3) << 3))];
                }
            }
        }
    }
}

// ---------------------------------------------------------------------------
// GEMM3: sampled(bf16) @ Wo + bo -> out fp32. 64x128 tiles (1050 blocks),
// LDS-repack f32 epilogue (r11/r12 proven): full 128 B lines.
// ---------------------------------------------------------------------------
__global__ __launch_bounds__(256, 4) void gemm_out(
    const ushort_t* __restrict__ A, const ushort_t* __restrict__ BT,
    const float* __restrict__ bo, float* __restrict__ out)
{
    __shared__ ushort_t smem[12288];   // A|B stage; epi: 32x128 f32 chunks
    ushort_t* Asl = smem;
    ushort_t* Bsl = smem + 4096;

    const int m0 = (blockIdx.x >> 1) * 64;     // adjacency swizzle (525x2)
    const int n0 = (blockIdx.x & 1) * 128;
    const int M = 33600;

    f32x4 acc[2][4];
    #pragma unroll
    for (int i = 0; i < 2; i++)
        #pragma unroll
        for (int j = 0; j < 4; j++) acc[i][j] = (f32x4){0.f, 0.f, 0.f, 0.f};

    gemm_core64(A, BT, M, m0, n0, Asl, Bsl, acc);

    const int tid  = threadIdx.x;
    const int wave = tid >> 6, lane = tid & 63;
    const int quad = lane >> 4, mr = lane & 15;
    const int half = wave >> 1;
    const int wn   = (wave & 1) * 64;
    float* fsm = (float*)smem;                 // 32 x 128 f32 = 16 KB

    #pragma unroll
    for (int i = 0; i < 2; i++) {
        __syncthreads();                       // prev chunk read / K-loop done
        #pragma unroll
        for (int j = 0; j < 4; j++) {
            const int lc = wn + j * 16 + mr;
            const float bias = bo[n0 + lc];
            #pragma unroll
            for (int reg = 0; reg < 4; reg++) {
                const int rloc = half * 16 + quad * 4 + reg;    // 0..31
                const int cs = lc ^ (quad << 4);                // bank spread
                fsm[rloc * 128 + cs] = acc[i][j][reg] + bias;
            }
        }
        __syncthreads();
        // 1024 float4 stores: 32 rows x 32 segs, 512 B contiguous per row
        #pragma unroll
        for (int k = 0; k < 4; k++) {
            int sid = k * 256 + tid;
            int rloc = sid >> 5, cw = (sid & 31) * 4;
            int row = m0 + (rloc >> 4) * 32 + i * 16 + (rloc & 15);
            if (row >= M) continue;
            int q2 = (rloc >> 2) & 3;
            float4 v = *(const float4*)&fsm[rloc * 128 + (cw ^ (q2 << 4))];
            *(float4*)&out[(size_t)row * 256 + n0 + cw] = v;
        }
    }
}

// ---------------------------------------------------------------------------
// Sampler v10 (unchanged, proven ~47 µs): pair-interleaved gathers, plane-
// locality blocks (b, h, 32-query chunk), h = bid&7 XCD-pinned.
// ---------------------------------------------------------------------------
__global__ __launch_bounds__(256) void msda_sample(
    const ushort_t* __restrict__ vperm, const ushort_t* __restrict__ off,
    const ushort_t* __restrict__ awl, const float* __restrict__ refp,
    ushort_t* __restrict__ sampled)
{
    __shared__ int4 s_wi[16 * 33];   // (wt f16x2, wb f16x2, off_top, off_bot)

    const int tid = threadIdx.x;
    const int bid = blockIdx.x;
    const int h   = bid & 7;          // XCD-pinned head
    const int r   = bid >> 3;         // 0..1051
    const int b   = r / 263;
    const int c   = r - b * 263;      // chunk within batch
    const int q0b = c * 32;           // first query (within batch b)
    const size_t bq0 = (size_t)b * LQ + q0b;

    const int Hs[4]    = {80, 40, 20, 10};
    const int pbase[4] = {0, 3200, 4000, 4200};

    #pragma unroll
    for (int it = 0; it < 2; it++) {
        const int s  = it * 256 + tid;
        const int ql = s >> 4, lp = s & 15;
        const int l  = lp >> 2;
        const int qv = (q0b + ql < LQ) ? ql : 0;   // clamp tail chunk reads
        const size_t bq = bq0 + qv;
        const int Wl = Hs[l];

        unsigned od = *(const unsigned*)(off + bq * 256 + h * 32 + lp * 2);
        float ox = bflo(od), oy = bfhi(od);
        float lgt = bflo((unsigned)awl[bq * 128 + h * 16 + lp]);
        // softmax over the 16-lane (q) group, no max pass (bounded logits)
        float e = __expf(lgt);
        float sum = e;
        sum += __shfl_xor(sum, 1, 16);
        sum += __shfl_xor(sum, 2, 16);
        sum += __shfl_xor(sum, 4, 16);
        sum += __shfl_xor(sum, 8, 16);
        float aw = e * __builtin_amdgcn_rcpf(sum);

        float2 rp = *(const float2*)(refp + bq * 8 + l * 2);
        float x = rp.x * (float)Wl + ox - 0.5f;
        float y = rp.y * (float)Wl + oy - 0.5f;
        float x0f = floorf(x), y0f = floorf(y);
        float wx = x - x0f, wy = y - y0f;
        int x0 = (int)x0f, y0 = (int)y0f;
        float hx0 = ((x0 >= 0) & (x0 < Wl)) ? (1.f - wx) : 0.f;
        float hx1 = ((x0 + 1 >= 0) & (x0 + 1 < Wl)) ? wx : 0.f;
        float vy0w = ((y0 >= 0) & (y0 < Wl)) ? (1.f - wy) * aw : 0.f;
        float vy1w = ((y0 + 1 >= 0) & (y0 + 1 < Wl)) ? wy * aw : 0.f;
        // fold borders into a valid adjacent pair (px, px+1)
        int px = min(max(x0, 0), Wl - 2);
        float pl, pr;
        if (x0 < px)      { pl = hx1; pr = 0.f; }   // x0 left of grid
        else if (x0 > px) { pl = 0.f; pr = hx0; }   // x0 == Wl-1
        else              { pl = hx0; pr = hx1; }
        int cy0 = min(max(y0, 0), Wl - 1);
        int cy1 = min(max(y0 + 1, 0), Wl - 1);
        const int copy = px & 1;
        const int p    = copy ? ((px - 1) >> 1) : (px >> 1);
        const int rowp = Wl >> 1;
        const int cb   = copy * 4250 + pbase[l] + p;
        const int otop = (cb + cy0 * rowp) << 7;    // pair byte offsets
        const int obot = (cb + cy1 * rowp) << 7;
        unsigned wt = pk2u(__builtin_amdgcn_cvt_pkrtz(pl * vy0w, pr * vy0w));
        unsigned wb = pk2u(__builtin_amdgcn_cvt_pkrtz(pl * vy1w, pr * vy1w));
        s_wi[lp * 33 + ql] = make_int4((int)wt, (int)wb, otop, obot);
    }
    __syncthreads();

    const int ql  = tid >> 3;          // 0..31
    const int l8  = tid & 7;
    const int dby = l8 * 16;           // byte offset of this lane's 4-dim pair block

    if (q0b + ql < LQ) {
        const char* plane = (const char*)(vperm + (size_t)(b * NH + h) * PLANE_USH);
        float a0 = 0.f, a1 = 0.f, a2 = 0.f, a3 = 0.f;
        #pragma unroll
        for (int pt = 0; pt < 16; pt++) {
            int4 wi = s_wi[pt * 33 + ql];
            uint4 vt = *(const uint4*)(plane + (unsigned)(wi.z + dby));
            uint4 vb = *(const uint4*)(plane + (unsigned)(wi.w + dby));
            half2_t wt = ash2((unsigned)wi.x);
            half2_t wb = ash2((unsigned)wi.y);
            a0 = __builtin_amdgcn_fdot2(wt, ash2(vt.x), a0, false);
            a0 = __builtin_amdgcn_fdot2(wb, ash2(vb.x), a0, false);
            a1 = __builtin_amdgcn_fdot2(wt, ash2(vt.y), a1, false);
            a1 = __builtin_amdgcn_fdot2(wb, ash2(vb.y), a1, false);
            a2 = __builtin_amdgcn_fdot2(wt, ash2(vt.z), a2, false);
            a2 = __builtin_amdgcn_fdot2(wb, ash2(vb.z), a2, false);
            a3 = __builtin_amdgcn_fdot2(wt, ash2(vt.w), a3, false);
            a3 = __builtin_amdgcn_fdot2(wb, ash2(vb.w), a3, false);
        }
        const size_t bq = bq0 + ql;
        ushort4 o;
        o.x = f2bf(a0); o.y = f2bf(a1);
        o.z = f2bf(a2); o.w = f2bf(a3);
        *(ushort4*)(sampled + bq * 256 + h * 32 + l8 * 4) = o;
    }
}

extern "C" void kernel_launch(void* const* d_in, const int* in_sizes, int n_in,
                              void* d_out, int out_size, void* d_ws, size_t ws_size,
                              hipStream_t stream) {
    const float* query = (const float*)d_in[0];
    const float* refp  = (const float*)d_in[1];
    const float* value = (const float*)d_in[2];
    const float* Wv    = (const float*)d_in[4];
    const float* bv    = (const float*)d_in[5];
    const float* Woff  = (const float*)d_in[6];
    const float* boff  = (const float*)d_in[7];
    const float* Wattn = (const float*)d_in[8];
    const float* battn = (const float*)d_in[9];
    const float* Wo    = (const float*)d_in[10];
    const float* bo    = (const float*)d_in[11];
    float* out = (float*)d_out;

    // Workspace (78.3 MB): off 17.2 + awl 8.6 + vperm(pair x2) 34.8
    //                      + BT 0.46 + sampled 17.2
    ushort_t* ws = (ushort_t*)d_ws;
    ushort_t* off_b   = ws;                       // 33600*256
    ushort_t* awl_b   = off_b + 8601600;          // 33600*128
    ushort_t* vperm_b = awl_b + 4300800;          // 32 planes * 544000 (f16 pairs)
    ushort_t* BT      = vperm_b + 17408000;       // 896*256
    ushort_t* sampled_b = BT + 229376;            // 33600*256 bf16

    prep_bt<<<dim3(896), 256, 0, stream>>>(Wv, Woff, Wattn, Wo, BT);

    gemm_fused<<<dim3(1064 + 1575), 256, 0, stream>>>(
        value, query, BT, bv, boff, battn, vperm_b, off_b, awl_b);

    msda_sample<<<dim3(8 * 4 * 263), 256, 0, stream>>>(
        vperm_b, off_b, awl_b, refp, sampled_b);

    gemm_out<<<dim3(1050), 256, 0, stream>>>(
        sampled_b, BT + 163840, bo, out);
}

// Round 14
// 203.601 us; speedup vs baseline: 1.3913x; 1.0172x over previous
//
#include <hip/hip_runtime.h>
#include <math.h>

#define BB 4
#define LQ 8400
#define NH 8
#define LVTOT 8500
#define HD 32
#define PLANE_USH 544000   // 8500 pairs x 64 ushorts (2 parity copies of 4250)

typedef __attribute__((ext_vector_type(8))) short short8;
typedef __attribute__((ext_vector_type(4))) float f32x4;
typedef __attribute__((ext_vector_type(2))) _Float16 half2_t;
typedef __attribute__((ext_vector_type(2))) __fp16 fp16x2_t;
typedef unsigned short ushort_t;

__device__ __forceinline__ ushort_t f2bf(float f) {
    union { float f; unsigned u; } v; v.f = f;
    unsigned r = v.u + 0x7fffu + ((v.u >> 16) & 1u);   // RNE
    return (ushort_t)(r >> 16);
}
__device__ __forceinline__ float bflo(unsigned u) {
    union { unsigned u; float f; } x; x.u = u << 16; return x.f;
}
__device__ __forceinline__ float bfhi(unsigned u) {
    union { unsigned u; float f; } x; x.u = u & 0xffff0000u; return x.f;
}
__device__ __forceinline__ half2_t ash2(unsigned u) {
    union { unsigned u; half2_t h; } x; x.u = u; return x.h;
}
__device__ __forceinline__ unsigned pk2u(fp16x2_t h) {
    union { fp16x2_t h; unsigned u; } x; x.h = h; return x.u;
}

// async global->LDS DMA, 16 B per lane (wave-uniform LDS base + lane*16)
__device__ __forceinline__ void dma16(const ushort_t* g, ushort_t* l) {
    __builtin_amdgcn_global_load_lds(
        (const __attribute__((address_space(1))) void*)g,
        (__attribute__((address_space(3))) void*)l, 16, 0, 0);
}
__device__ __forceinline__ void dma16g(const void* g, void* l) {
    __builtin_amdgcn_global_load_lds(
        (const __attribute__((address_space(1))) void*)g,
        (__attribute__((address_space(3))) void*)l, 16, 0, 0);
}

// level decomposition of a pixel index (0..8499) -> pair-space geometry
__device__ __forceinline__ void lvl_decomp(int pix, int& lb, int& y, int& x,
                                           int& rowp) {
    if (pix < 6400)      { y = pix / 80;            x = pix - y * 80;  rowp = 40; lb = 0; }
    else if (pix < 8000) { int r = pix - 6400; y = r / 40; x = r - y * 40; rowp = 20; lb = 3200; }
    else if (pix < 8400) { int r = pix - 8000; y = r / 20; x = r - y * 20; rowp = 10; lb = 4000; }
    else                 { int r = pix - 8400; y = r / 10; x = r - y * 10; rowp = 5;  lb = 4200; }
}

// ---------------------------------------------------------------------------
// prep_bt: BT build only (896 blocks).
// ---------------------------------------------------------------------------
__global__ __launch_bounds__(256) void prep_bt(
    const float* __restrict__ Wv, const float* __restrict__ Woff,
    const float* __restrict__ Wattn, const float* __restrict__ Wo,
    ushort_t* __restrict__ BT)
{
    int idx = blockIdx.x * 256 + threadIdx.x;   // 896*256
    int r = idx >> 8, k = idx & 255;
    float v;
    if (r < 256) v = Wv[k * 256 + r];
    else if (r < 640) {
        int n = r - 256;
        v = (n < 256) ? Woff[k * 256 + n] : Wattn[k * 128 + (n - 256)];
    } else v = Wo[k * 256 + (r - 640)];
    BT[idx] = f2bf(v);
}

// ---------------------------------------------------------------------------
// GEMM core (f32-A, templated N width): 64 x (NF*32) tile, 4 waves
// (2M x 2N, wave = 32 x NF*16), BK=64, serial 2-barrier loop. A staged f32
// once per K-step (single n-pass per panel now); in-register f2bf (bit-
// identical to pre-cast). B staged bf16 from BT.
// ---------------------------------------------------------------------------
template<int NF>
__device__ __forceinline__ void gcore_f32a(
    const float* __restrict__ A, const ushort_t* __restrict__ B, int M,
    int m0, float* Af, ushort_t* Bsl, f32x4 acc[2][NF])
{
    const int tid  = threadIdx.x;
    const int wave = tid >> 6, lane = tid & 63;
    const int quad = lane >> 4, mr = lane & 15;
    const int wm   = (wave >> 1) * 32, wn = (wave & 1) * (NF * 16);
    const int oct  = lane >> 3;       // B path: 8 rows/slab
    const int bseg = lane & 7;
    const int r4   = lane >> 4;       // A path: 4 rows/slab
    const int s16  = lane & 15;       // 16 x 16B segs per 256 B row

    for (int k0 = 0; k0 < 256; k0 += 64) {
        __syncthreads();              // prior iteration's reads done
        // A: 64 rows x 64 floats, 4 passes x 16 rows
        #pragma unroll
        for (int i = 0; i < 4; i++) {
            int m  = i * 16 + wave * 4 + r4;
            int gs = s16 ^ (m & 15);                   // swizzled source seg
            int am = min(m0 + m, M - 1);
            dma16g((const char*)A + (size_t)am * 1024 + (size_t)(k0 + gs * 4) * 4,
                   (char*)Af + (i * 16 + wave * 4) * 256 + lane * 16);
        }
        // B: NF*32 rows bf16, NF passes x 32 rows
        #pragma unroll
        for (int i = 0; i < NF; i++) {
            int n  = i * 32 + wave * 8 + oct;
            int gs = bseg ^ (n & 7);
            dma16(B + (size_t)n * 256 + k0 + gs * 8,
                  Bsl + (i * 32 + wave * 8) * 64 + lane * 8);
        }
        __syncthreads();              // DMA landed
        #pragma unroll
        for (int ks = 0; ks < 2; ks++) {
            short8 af[2], bf[NF];
            const int ksl = ks * 4 + quad;
            #pragma unroll
            for (int i = 0; i < 2; i++) {
                int m  = wm + i * 16 + mr;
                int p0 = (ksl * 2) ^ (m & 15);
                int p1 = (ksl * 2 + 1) ^ (m & 15);
                float4 lo = *(const float4*)&Af[m * 64 + p0 * 4];
                float4 hi = *(const float4*)&Af[m * 64 + p1 * 4];
                short8 a;
                a[0] = (short)f2bf(lo.x); a[1] = (short)f2bf(lo.y);
                a[2] = (short)f2bf(lo.z); a[3] = (short)f2bf(lo.w);
                a[4] = (short)f2bf(hi.x); a[5] = (short)f2bf(hi.y);
                a[6] = (short)f2bf(hi.z); a[7] = (short)f2bf(hi.w);
                af[i] = a;
            }
            #pragma unroll
            for (int j = 0; j < NF; j++) {
                int n = wn + j * 16 + mr;
                bf[j] = *(const short8*)&Bsl[n * 64 + (ksl ^ (n & 7)) * 8];
            }
            #pragma unroll
            for (int i = 0; i < 2; i++)
                #pragma unroll
                for (int j = 0; j < NF; j++)
                    acc[i][j] = __builtin_amdgcn_mfma_f32_16x16x32_bf16(
                        af[i], bf[j], acc[i][j], 0, 0, 0);
        }
    }
}

// ---------------------------------------------------------------------------
// GEMM core v5 (bf16-A, proven r12): used by gemm_out (A = sampled bf16).
// ---------------------------------------------------------------------------
__device__ __forceinline__ void gemm_core64(
    const ushort_t* __restrict__ A, const ushort_t* __restrict__ B, int M,
    int m0, int n0, ushort_t* Asl, ushort_t* Bsl, f32x4 acc[2][4])
{
    const int tid  = threadIdx.x;
    const int wave = tid >> 6, lane = tid & 63;
    const int quad = lane >> 4, mr = lane & 15;
    const int wm   = (wave >> 1) * 32, wn = (wave & 1) * 64;
    const int oct  = lane >> 3;
    const int bseg = lane & 7;

    for (int k0 = 0; k0 < 256; k0 += 64) {
        __syncthreads();
        #pragma unroll
        for (int i = 0; i < 2; i++) {                 // A: 64 rows
            int m  = i * 32 + wave * 8 + oct;
            int gs = bseg ^ (m & 7);
            int am = min(m0 + m, M - 1);
            dma16(A + (size_t)am * 256 + k0 + gs * 8,
                  Asl + (i * 32 + wave * 8) * 64 + lane * 8);
        }
        #pragma unroll
        for (int i = 0; i < 4; i++) {                 // B: 128 rows
            int n  = i * 32 + wave * 8 + oct;
            int gs = bseg ^ (n & 7);
            dma16(B + (size_t)(n0 + n) * 256 + k0 + gs * 8,
                  Bsl + (i * 32 + wave * 8) * 64 + lane * 8);
        }
        __syncthreads();
        #pragma unroll
        for (int ks = 0; ks < 2; ks++) {
            short8 af[2], bf[4];
            const int ksl = ks * 4 + quad;
            #pragma unroll
            for (int i = 0; i < 2; i++) {
                int m = wm + i * 16 + mr;
                af[i] = *(const short8*)&Asl[m * 64 + (ksl ^ (m & 7)) * 8];
            }
            #pragma unroll
            for (int j = 0; j < 4; j++) {
                int n = wn + j * 16 + mr;
                bf[j] = *(const short8*)&Bsl[n * 64 + (ksl ^ (n & 7)) * 8];
            }
            #pragma unroll
            for (int i = 0; i < 2; i++)
                #pragma unroll
                for (int j = 0; j < 4; j++)
                    acc[i][j] = __builtin_amdgcn_mfma_f32_16x16x32_bf16(
                        af[i], bf[j], acc[i][j], 0, 0, 0);
        }
    }
}

// ---------------------------------------------------------------------------
// gemm_fused: full-width N tiles (stage A once per panel).
//  bid <  532: mode0  value f32 -> vperm, 64x256 (all 8 heads)
//  bid < 1057: mode1a query f32 -> off (cols 0..255), 64x256
//  else      : mode1b query f32 -> awl (BT rows 512..639), 64x128
// LDS 48 KB (A f32 16 KB + B bf16 32 KB), 3 blocks/CU — same effective
// occupancy as r13's 32 KB @ ~3.75 blocks, but drains/fetch per output
// halved (mode0/1a) and A panels fetched once (value) / twice (query).
// ---------------------------------------------------------------------------
__global__ __launch_bounds__(256, 3) void gemm_fused(
    const float* __restrict__ Av, const float* __restrict__ Aq,
    const ushort_t* __restrict__ BT,
    const float* __restrict__ bv, const float* __restrict__ boff,
    const float* __restrict__ battn,
    ushort_t* __restrict__ vperm, ushort_t* __restrict__ off_b,
    ushort_t* __restrict__ awl_b)
{
    __shared__ ushort_t smem[24576];   // A f32 16 KB | B bf16 32 KB; epi reuse
    float*    Af  = (float*)smem;
    ushort_t* Bsl = smem + 8192;

    const int bid  = blockIdx.x;
    const int tid  = threadIdx.x;
    const int wave = tid >> 6, lane = tid & 63;
    const int quad = lane >> 4, mr = lane & 15;
    const int wm   = (wave >> 1) * 32;

    if (bid < 532) {
        // ---------------- mode0: value -> vperm (64x256) ----------------
        const int m0 = bid * 64;
        f32x4 acc[2][8];
        #pragma unroll
        for (int i = 0; i < 2; i++)
            #pragma unroll
            for (int j = 0; j < 8; j++) acc[i][j] = (f32x4){0.f, 0.f, 0.f, 0.f};
        gcore_f32a<8>(Av, BT, 34000, m0, Af, Bsl, acc);

        const int wn = (wave & 1) * 128;
        __syncthreads();
        #pragma unroll
        for (int i = 0; i < 2; i++) {
            #pragma unroll
            for (int j = 0; j < 8; j++) {
                const int lc = wn + j * 16 + mr;       // 0..255
                const float bias = bv[lc];
                #pragma unroll
                for (int reg = 0; reg < 4; reg++) {
                    const int rl = wm + i * 16 + quad * 4 + reg;   // 0..63
                    union { _Float16 h; ushort_t u; } cv;
                    cv.h = (_Float16)(acc[i][j][reg] + bias);
                    smem[rl * 256 + (lc ^ ((rl & 3) << 3))] = cv.u;
                }
            }
        }
        __syncthreads();
        // pair stores: 63 units x 64 subs (hh 0..7, q 0..7)
        for (int k = 0; k < 16; k++) {
            int sid = k * 256 + tid;
            int unit = sid >> 6;
            if (unit >= 63) continue;
            int sub = sid & 63;
            int hh = sub >> 3, q = sub & 7;
            int copy = (unit >= 32) ? 1 : 0;
            int t = copy ? ((unit - 32) * 2 + 1) : (unit * 2);
            int row = m0 + t;
            if (row + 1 >= 34000) continue;
            int b = row / LVTOT, pix = row - b * LVTOT;
            int lb, y, x, rowp;
            lvl_decomp(pix, lb, y, x, rowp);
            if (copy && x >= 2 * rowp - 1) continue;   // wrap pair
            int p = x >> 1;
            int pidx = copy * 4250 + lb + y * rowp + p;
            uint2 a  = *(const uint2*)&smem[t * 256 +
                          ((hh * 32 + q * 4) ^ ((t & 3) << 3))];
            uint2 b2 = *(const uint2*)&smem[(t + 1) * 256 +
                          ((hh * 32 + q * 4) ^ (((t + 1) & 3) << 3))];
            uint4 o;
            o.x = (a.x & 0xffffu) | (b2.x << 16);
            o.y = (a.x >> 16)     | (b2.x & 0xffff0000u);
            o.z = (a.y & 0xffffu) | (b2.y << 16);
            o.w = (a.y >> 16)     | (b2.y & 0xffff0000u);
            *(uint4*)((char*)(vperm + (size_t)(b * NH + hh) * PLANE_USH)
                      + (size_t)pidx * 128 + q * 16) = o;
        }
        // boundary scatters: t=0 -> slot1 of left pair; t=63 -> slot0
        for (int it = 0; it < 2; it++) {
            int s = it * 256 + tid;            // 512 slots
            int pixsel = s >> 8;
            int rem = s & 255;
            int hh = rem >> 5, d = rem & 31;
            int t = pixsel ? 63 : 0;
            int row = m0 + t;
            if (row < 34000) {
                int b = row / LVTOT, pix = row - b * LVTOT;
                int lb, y, x, rowp;
                lvl_decomp(pix, lb, y, x, rowp);
                bool doit; int p, slot;
                if (!pixsel) { doit = (x >= 2);            p = (x - 2) >> 1; slot = 1; }
                else         { doit = (x < 2 * rowp - 1);  p = (x - 1) >> 1; slot = 0; }
                if (doit) {
                    int pidx = 4250 + lb + y * rowp + p;
                    vperm[(size_t)(b * NH + hh) * PLANE_USH
                          + (size_t)pidx * 64 + d * 2 + slot] =
                        smem[t * 256 + ((hh * 32 + d) ^ ((t & 3) << 3))];
                }
            }
        }
    } else if (bid < 1057) {
        // ---------------- mode1a: query -> off cols 0..255 (64x256) -----
        const int m0 = (bid - 532) * 64;
        f32x4 acc[2][8];
        #pragma unroll
        for (int i = 0; i < 2; i++)
            #pragma unroll
            for (int j = 0; j < 8; j++) acc[i][j] = (f32x4){0.f, 0.f, 0.f, 0.f};
        gcore_f32a<8>(Aq, BT + 65536, 33600, m0, Af, Bsl, acc);

        const int wn = (wave & 1) * 128;
        __syncthreads();
        #pragma unroll
        for (int i = 0; i < 2; i++) {
            #pragma unroll
            for (int j = 0; j < 8; j++) {
                const int lc = wn + j * 16 + mr;
                const float bias = boff[lc];
                #pragma unroll
                for (int reg = 0; reg < 4; reg++) {
                    const int rl = wm + i * 16 + quad * 4 + reg;
                    smem[rl * 256 + (lc ^ ((rl & 3) << 3))] =
                        f2bf(acc[i][j][reg] + bias);
                }
            }
        }
        __syncthreads();
        #pragma unroll
        for (int k = 0; k < 8; k++) {
            int sid = k * 256 + tid;            // 2048 x 16B
            int rl = sid >> 5, cc = (sid & 31) * 8;
            int row = m0 + rl;
            if (row >= 33600) continue;
            uint4 v = *(const uint4*)&smem[rl * 256 + (cc ^ ((rl & 3) << 3))];
            *(uint4*)&off_b[(size_t)row * 256 + cc] = v;
        }
    } else {
        // ---------------- mode1b: query -> awl (64x128) ------------------
        const int m0 = (bid - 1057) * 64;
        f32x4 acc[2][4];
        #pragma unroll
        for (int i = 0; i < 2; i++)
            #pragma unroll
            for (int j = 0; j < 4; j++) acc[i][j] = (f32x4){0.f, 0.f, 0.f, 0.f};
        gcore_f32a<4>(Aq, BT + 131072, 33600, m0, Af, Bsl, acc);

        const int wn = (wave & 1) * 64;
        __syncthreads();
        #pragma unroll
        for (int i = 0; i < 2; i++) {
            #pragma unroll
            for (int j = 0; j < 4; j++) {
                const int lc = wn + j * 16 + mr;       // 0..127
                const float bias = battn[lc];
                #pragma unroll
                for (int reg = 0; reg < 4; reg++) {
                    const int rl = wm + i * 16 + quad * 4 + reg;
                    smem[rl * 128 + (lc ^ ((rl & 3) << 3))] =
                        f2bf(acc[i][j][reg] + bias);
                }
            }
        }
        __syncthreads();
        #pragma unroll
        for (int k = 0; k < 4; k++) {
            int sid = k * 256 + tid;            // 1024 x 16B
            int rl = sid >> 4, cc = (sid & 15) * 8;
            int row = m0 + rl;
            if (row >= 33600) continue;
            uint4 v = *(const uint4*)&smem[rl * 128 + (cc ^ ((rl & 3) << 3))];
            *(uint4*)&awl_b[(size_t)row * 128 + cc] = v;
        }
    }
}

// ---------------------------------------------------------------------------
// GEMM3: sampled(bf16) @ Wo + bo -> out fp32. 64x128 tiles (1050 blocks),
// LDS-repack f32 epilogue (r11/r12 proven): full 128 B lines.
// ---------------------------------------------------------------------------
__global__ __launch_bounds__(256, 4) void gemm_out(
    const ushort_t* __restrict__ A, const ushort_t* __restrict__ BT,
    const float* __restrict__ bo, float* __restrict__ out)
{
    __shared__ ushort_t smem[12288];   // A|B stage; epi: 32x128 f32 chunks
    ushort_t* Asl = smem;
    ushort_t* Bsl = smem + 4096;

    const int m0 = (blockIdx.x >> 1) * 64;     // adjacency swizzle (525x2)
    const int n0 = (blockIdx.x & 1) * 128;
    const int M = 33600;

    f32x4 acc[2][4];
    #pragma unroll
    for (int i = 0; i < 2; i++)
        #pragma unroll
        for (int j = 0; j < 4; j++) acc[i][j] = (f32x4){0.f, 0.f, 0.f, 0.f};

    gemm_core64(A, BT, M, m0, n0, Asl, Bsl, acc);

    const int tid  = threadIdx.x;
    const int wave = tid >> 6, lane = tid & 63;
    const int quad = lane >> 4, mr = lane & 15;
    const int half = wave >> 1;
    const int wn   = (wave & 1) * 64;
    float* fsm = (float*)smem;                 // 32 x 128 f32 = 16 KB

    #pragma unroll
    for (int i = 0; i < 2; i++) {
        __syncthreads();                       // prev chunk read / K-loop done
        #pragma unroll
        for (int j = 0; j < 4; j++) {
            const int lc = wn + j * 16 + mr;
            const float bias = bo[n0 + lc];
            #pragma unroll
            for (int reg = 0; reg < 4; reg++) {
                const int rloc = half * 16 + quad * 4 + reg;    // 0..31
                const int cs = lc ^ (quad << 4);                // bank spread
                fsm[rloc * 128 + cs] = acc[i][j][reg] + bias;
            }
        }
        __syncthreads();
        // 1024 float4 stores: 32 rows x 32 segs, 512 B contiguous per row
        #pragma unroll
        for (int k = 0; k < 4; k++) {
            int sid = k * 256 + tid;
            int rloc = sid >> 5, cw = (sid & 31) * 4;
            int row = m0 + (rloc >> 4) * 32 + i * 16 + (rloc & 15);
            if (row >= M) continue;
            int q2 = (rloc >> 2) & 3;
            float4 v = *(const float4*)&fsm[rloc * 128 + (cw ^ (q2 << 4))];
            *(float4*)&out[(size_t)row * 256 + n0 + cw] = v;
        }
    }
}

// ---------------------------------------------------------------------------
// Sampler v10 (unchanged, proven ~47 µs): pair-interleaved gathers, plane-
// locality blocks (b, h, 32-query chunk), h = bid&7 XCD-pinned.
// ---------------------------------------------------------------------------
__global__ __launch_bounds__(256) void msda_sample(
    const ushort_t* __restrict__ vperm, const ushort_t* __restrict__ off,
    const ushort_t* __restrict__ awl, const float* __restrict__ refp,
    ushort_t* __restrict__ sampled)
{
    __shared__ int4 s_wi[16 * 33];   // (wt f16x2, wb f16x2, off_top, off_bot)

    const int tid = threadIdx.x;
    const int bid = blockIdx.x;
    const int h   = bid & 7;          // XCD-pinned head
    const int r   = bid >> 3;         // 0..1051
    const int b   = r / 263;
    const int c   = r - b * 263;      // chunk within batch
    const int q0b = c * 32;           // first query (within batch b)
    const size_t bq0 = (size_t)b * LQ + q0b;

    const int Hs[4]    = {80, 40, 20, 10};
    const int pbase[4] = {0, 3200, 4000, 4200};

    #pragma unroll
    for (int it = 0; it < 2; it++) {
        const int s  = it * 256 + tid;
        const int ql = s >> 4, lp = s & 15;
        const int l  = lp >> 2;
        const int qv = (q0b + ql < LQ) ? ql : 0;   // clamp tail chunk reads
        const size_t bq = bq0 + qv;
        const int Wl = Hs[l];

        unsigned od = *(const unsigned*)(off + bq * 256 + h * 32 + lp * 2);
        float ox = bflo(od), oy = bfhi(od);
        float lgt = bflo((unsigned)awl[bq * 128 + h * 16 + lp]);
        // softmax over the 16-lane (q) group, no max pass (bounded logits)
        float e = __expf(lgt);
        float sum = e;
        sum += __shfl_xor(sum, 1, 16);
        sum += __shfl_xor(sum, 2, 16);
        sum += __shfl_xor(sum, 4, 16);
        sum += __shfl_xor(sum, 8, 16);
        float aw = e * __builtin_amdgcn_rcpf(sum);

        float2 rp = *(const float2*)(refp + bq * 8 + l * 2);
        float x = rp.x * (float)Wl + ox - 0.5f;
        float y = rp.y * (float)Wl + oy - 0.5f;
        float x0f = floorf(x), y0f = floorf(y);
        float wx = x - x0f, wy = y - y0f;
        int x0 = (int)x0f, y0 = (int)y0f;
        float hx0 = ((x0 >= 0) & (x0 < Wl)) ? (1.f - wx) : 0.f;
        float hx1 = ((x0 + 1 >= 0) & (x0 + 1 < Wl)) ? wx : 0.f;
        float vy0w = ((y0 >= 0) & (y0 < Wl)) ? (1.f - wy) * aw : 0.f;
        float vy1w = ((y0 + 1 >= 0) & (y0 + 1 < Wl)) ? wy * aw : 0.f;
        // fold borders into a valid adjacent pair (px, px+1)
        int px = min(max(x0, 0), Wl - 2);
        float pl, pr;
        if (x0 < px)      { pl = hx1; pr = 0.f; }   // x0 left of grid
        else if (x0 > px) { pl = 0.f; pr = hx0; }   // x0 == Wl-1
        else              { pl = hx0; pr = hx1; }
        int cy0 = min(max(y0, 0), Wl - 1);
        int cy1 = min(max(y0 + 1, 0), Wl - 1);
        const int copy = px & 1;
        const int p    = copy ? ((px - 1) >> 1) : (px >> 1);
        const int rowp = Wl >> 1;
        const int cb   = copy * 4250 + pbase[l] + p;
        const int otop = (cb + cy0 * rowp) << 7;    // pair byte offsets
        const int obot = (cb + cy1 * rowp) << 7;
        unsigned wt = pk2u(__builtin_amdgcn_cvt_pkrtz(pl * vy0w, pr * vy0w));
        unsigned wb = pk2u(__builtin_amdgcn_cvt_pkrtz(pl * vy1w, pr * vy1w));
        s_wi[lp * 33 + ql] = make_int4((int)wt, (int)wb, otop, obot);
    }
    __syncthreads();

    const int ql  = tid >> 3;          // 0..31
    const int l8  = tid & 7;
    const int dby = l8 * 16;           // byte offset of this lane's 4-dim pair block

    if (q0b + ql < LQ) {
        const char* plane = (const char*)(vperm + (size_t)(b * NH + h) * PLANE_USH);
        float a0 = 0.f, a1 = 0.f, a2 = 0.f, a3 = 0.f;
        #pragma unroll
        for (int pt = 0; pt < 16; pt++) {
            int4 wi = s_wi[pt * 33 + ql];
            uint4 vt = *(const uint4*)(plane + (unsigned)(wi.z + dby));
            uint4 vb = *(const uint4*)(plane + (unsigned)(wi.w + dby));
            half2_t wt = ash2((unsigned)wi.x);
            half2_t wb = ash2((unsigned)wi.y);
            a0 = __builtin_amdgcn_fdot2(wt, ash2(vt.x), a0, false);
            a0 = __builtin_amdgcn_fdot2(wb, ash2(vb.x), a0, false);
            a1 = __builtin_amdgcn_fdot2(wt, ash2(vt.y), a1, false);
            a1 = __builtin_amdgcn_fdot2(wb, ash2(vb.y), a1, false);
            a2 = __builtin_amdgcn_fdot2(wt, ash2(vt.z), a2, false);
            a2 = __builtin_amdgcn_fdot2(wb, ash2(vb.z), a2, false);
            a3 = __builtin_amdgcn_fdot2(wt, ash2(vt.w), a3, false);
            a3 = __builtin_amdgcn_fdot2(wb, ash2(vb.w), a3, false);
        }
        const size_t bq = bq0 + ql;
        ushort4 o;
        o.x = f2bf(a0); o.y = f2bf(a1);
        o.z = f2bf(a2); o.w = f2bf(a3);
        *(ushort4*)(sampled + bq * 256 + h * 32 + l8 * 4) = o;
    }
}

extern "C" void kernel_launch(void* const* d_in, const int* in_sizes, int n_in,
                              void* d_out, int out_size, void* d_ws, size_t ws_size,
                              hipStream_t stream) {
    const float* query = (const float*)d_in[0];
    const float* refp  = (const float*)d_in[1];
    const float* value = (const float*)d_in[2];
    const float* Wv    = (const float*)d_in[4];
    const float* bv    = (const float*)d_in[5];
    const float* Woff  = (const float*)d_in[6];
    const float* boff  = (const float*)d_in[7];
    const float* Wattn = (const float*)d_in[8];
    const float* battn = (const float*)d_in[9];
    const float* Wo    = (const float*)d_in[10];
    const float* bo    = (const float*)d_in[11];
    float* out = (float*)d_out;

    // Workspace (78.3 MB): off 17.2 + awl 8.6 + vperm(pair x2) 34.8
    //                      + BT 0.46 + sampled 17.2
    ushort_t* ws = (ushort_t*)d_ws;
    ushort_t* off_b   = ws;                       // 33600*256
    ushort_t* awl_b   = off_b + 8601600;          // 33600*128
    ushort_t* vperm_b = awl_b + 4300800;          // 32 planes * 544000 (f16 pairs)
    ushort_t* BT      = vperm_b + 17408000;       // 896*256
    ushort_t* sampled_b = BT + 229376;            // 33600*256 bf16

    prep_bt<<<dim3(896), 256, 0, stream>>>(Wv, Woff, Wattn, Wo, BT);

    gemm_fused<<<dim3(1582), 256, 0, stream>>>(
        value, query, BT, bv, boff, battn, vperm_b, off_b, awl_b);

    msda_sample<<<dim3(8 * 4 * 263), 256, 0, stream>>>(
        vperm_b, off_b, awl_b, refp, sampled_b);

    gemm_out<<<dim3(1050), 256, 0, stream>>>(
        sampled_b, BT + 163840, bo, out);
}